// Round 11
// baseline (278.031 us; speedup 1.0000x reference)
//
#include <hip/hip_runtime.h>
#include <hip/hip_bf16.h>

#define HWN    1024
#define CCH    512
#define NBATCH 16
#define NGROUP 32
#define EPSV   1e-5f

using bf16 = __hip_bfloat16;
typedef __attribute__((ext_vector_type(4))) float f32x4;
typedef __attribute__((ext_vector_type(8))) short s16x8;

__device__ __forceinline__ float ldv(const void* p, long i, int c) {
    return c ? ((const float*)p)[i] : __bfloat162float(((const bf16*)p)[i]);
}
__device__ __forceinline__ void stv(void* p, long i, int c, float v) {
    if (c) ((float*)p)[i] = v;
    else   ((bf16*)p)[i]  = __float2bfloat16(v);
}
__device__ __forceinline__ float b2f(short s) {
    return __uint_as_float(((unsigned)(unsigned short)s) << 16);
}

// async global->LDS, 16B per lane; lds dest = wave-uniform base + lane*16
__device__ __forceinline__ void glds16(const void* g, void* l) {
    __builtin_amdgcn_global_load_lds(
        (const __attribute__((address_space(1))) void*)g,
        (__attribute__((address_space(3))) void*)l, 16, 0, 0);
}

// ---------------------------------------------------------------------------
// Storage dtype detector. flag=1 => fp32 storage.
// ---------------------------------------------------------------------------
__global__ __launch_bounds__(256) void detect_kernel(const void* __restrict__ x,
                                                     int* __restrict__ flag)
{
    const int tid = threadIdx.x;
    const unsigned short* h = (const unsigned short*)x;
    int ok = 0;
    for (int i = tid; i < 4096; i += 256) {
        int e = (h[2 * i] >> 7) & 0xFF;
        if (e >= 100 && e <= 135) ok++;
    }
    __shared__ int red[256];
    red[tid] = ok; __syncthreads();
    for (int off = 128; off > 0; off >>= 1) {
        if (tid < off) red[tid] += red[tid + off];
        __syncthreads();
    }
    if (tid == 0) flag[0] = (red[0] < 2458) ? 1 : 0;
}

// ---------------------------------------------------------------------------
// MEGA1 device bodies (R10): gn_stats || prep_t || micro_raw || zero-uv.
// All depend only on flag; merged into one launch for concurrency.
// pool: shared float[4160] unioned across roles.
// ---------------------------------------------------------------------------
__device__ __forceinline__
void gn_stats_dev(const void* __restrict__ x, int f, float2* __restrict__ stats,
                  int bidx, float* pool)
{
    const int b = bidx >> 5, g = bidx & 31;
    const long base = ((long)b * CCH + (long)g * (CCH / NGROUP)) * HWN;
    const int tid = threadIdx.x;
    const int n = (CCH / NGROUP) * HWN;       // 16384
    float s = 0.f, ss = 0.f;
    if (f) {
        const float4* xp = (const float4*)((const float*)x + base);
        #pragma unroll
        for (int k = 0; k < 16; ++k) {
            float4 u = xp[tid + k * 256];
            s  += u.x + u.y + u.z + u.w;
            ss += u.x * u.x + u.y * u.y + u.z * u.z + u.w * u.w;
        }
    } else {
        for (int i = tid; i < n; i += 256) {
            float v = ldv(x, base + i, 0);
            s += v; ss += v * v;
        }
    }
    float* r1 = pool;
    float* r2 = pool + 256;
    r1[tid] = s; r2[tid] = ss; __syncthreads();
    for (int off = 128; off > 0; off >>= 1) {
        if (tid < off) { r1[tid] += r1[tid + off]; r2[tid] += r2[tid + off]; }
        __syncthreads();
    }
    if (tid == 0) {
        float mean = r1[0] / n;
        float var  = r2[0] / n - mean * mean;
        stats[bidx] = make_float2(mean, rsqrtf(var + EPSV));
    }
}

__device__ __forceinline__
void prep_t_dev(const void* __restrict__ Wq, const void* __restrict__ Wk,
                const void* __restrict__ Wv, const void* __restrict__ Wo,
                int f, bf16* __restrict__ WkT, bf16* __restrict__ WqT,
                bf16* __restrict__ WvT, bf16* __restrict__ Wob,
                int idx, float* pool)
{
    const int tid = threadIdx.x;
    if (idx < 192) {
        const int mat = idx >> 6;           // 0:Wq->WqT 1:Wk->WkT 2:Wv->WvT
        const void* src = mat == 0 ? Wq : mat == 1 ? Wk : Wv;
        bf16* dst = mat == 0 ? WqT : mat == 1 ? WkT : WvT;
        const int tile = idx & 63;
        const int r0 = (tile >> 3) * 64, c0 = (tile & 7) * 64;
        const int il = tid & 63, hq = tid >> 6;
        #pragma unroll
        for (int rr = 0; rr < 16; ++rr) {
            const int r = rr * 4 + hq;
            pool[r * 65 + il] = ldv(src, (long)(r0 + r) * 512 + c0 + il, f);
        }
        __syncthreads();
        #pragma unroll
        for (int rr = 0; rr < 16; ++rr) {
            const int cc = rr * 4 + hq;
            dst[(long)(c0 + cc) * 512 + r0 + il] = __float2bfloat16(pool[il * 65 + cc]);
        }
    } else {
        // Wo copy: 64 blocks x 4096 elems; 8-elem vector chunks per thread.
        const int base = (idx - 192) * 4096;
        #pragma unroll
        for (int pass = 0; pass < 2; ++pass) {
            const int i = base + pass * 2048 + tid * 8;
            s16x8 out;
            if (f) {
                const float4* sp = (const float4*)Wo;
                const float4 a = sp[i >> 2];
                const float4 b = sp[(i >> 2) + 1];
                out[0] = (short)(ushort)__bfloat16_as_ushort(__float2bfloat16(a.x));
                out[1] = (short)(ushort)__bfloat16_as_ushort(__float2bfloat16(a.y));
                out[2] = (short)(ushort)__bfloat16_as_ushort(__float2bfloat16(a.z));
                out[3] = (short)(ushort)__bfloat16_as_ushort(__float2bfloat16(a.w));
                out[4] = (short)(ushort)__bfloat16_as_ushort(__float2bfloat16(b.x));
                out[5] = (short)(ushort)__bfloat16_as_ushort(__float2bfloat16(b.y));
                out[6] = (short)(ushort)__bfloat16_as_ushort(__float2bfloat16(b.z));
                out[7] = (short)(ushort)__bfloat16_as_ushort(__float2bfloat16(b.w));
            } else {
                out = *(const s16x8*)((const bf16*)Wo + i);
            }
            *(s16x8*)&Wob[i] = out;
        }
    }
}

// micro from RAW inputs (no prep_t dependency): w1 = Wk^T bq, w2 = Wq^T bk,
// b2 = Wo bv + bo, c0 = bq.bk; idx 7/8 zero rowB/colB (replaces memset).
__device__ __forceinline__
void micro_raw_dev(const void* __restrict__ Wq, const void* __restrict__ Wk,
                   const void* __restrict__ Wo,
                   const void* __restrict__ bq, const void* __restrict__ bk,
                   const void* __restrict__ bv, const void* __restrict__ bo,
                   int f, float* __restrict__ w1, float* __restrict__ w2,
                   float* __restrict__ b2, float* __restrict__ c0,
                   float* __restrict__ rowB, float* __restrict__ colB,
                   int idx, float* pool)
{
    const int tid = threadIdx.x;
    if (idx < 6) {
        const void* bsrc = idx < 2 ? bq : idx < 4 ? bk : bv;
        for (int i = tid; i < 512; i += 256) pool[i] = ldv(bsrc, i, f);
        __syncthreads();
        const int o = (idx & 1) * 256 + tid;
        float s = 0.f;
        if (idx < 4) {
            // column dot: coalesced across threads at each k
            const void* M = idx < 2 ? Wk : Wq;
            for (int k = 0; k < 512; ++k) s += ldv(M, (long)k * 512 + o, f) * pool[k];
            if (idx < 2) w1[o] = s; else w2[o] = s;
        } else {
            for (int k = 0; k < 512; ++k) s += ldv(Wo, (long)o * 512 + k, f) * pool[k];
            b2[o] = s + ldv(bo, o, f);
        }
    } else if (idx == 6) {
        float p = ldv(bq, tid, f) * ldv(bk, tid, f)
                + ldv(bq, tid + 256, f) * ldv(bk, tid + 256, f);
        pool[tid] = p; __syncthreads();
        for (int off = 128; off > 0; off >>= 1) {
            if (tid < off) pool[tid] += pool[tid + off];
            __syncthreads();
        }
        if (tid == 0) c0[0] = pool[0];
    } else {
        float4* d4 = (float4*)((idx == 7) ? rowB : colB);
        for (int i = tid; i < 4096; i += 256) d4[i] = make_float4(0.f, 0.f, 0.f, 0.f);
    }
}

__global__ __launch_bounds__(256)
void mega1_kernel(const void* __restrict__ x, const int* __restrict__ flag,
                  float2* __restrict__ stats,
                  const void* __restrict__ Wq, const void* __restrict__ Wk,
                  const void* __restrict__ Wv, const void* __restrict__ Wo,
                  const void* __restrict__ bq, const void* __restrict__ bk,
                  const void* __restrict__ bv, const void* __restrict__ bo,
                  bf16* __restrict__ WkT, bf16* __restrict__ WqT,
                  bf16* __restrict__ WvT, bf16* __restrict__ Wob,
                  float* __restrict__ w1, float* __restrict__ w2,
                  float* __restrict__ b2, float* __restrict__ c0,
                  float* __restrict__ rowB, float* __restrict__ colB)
{
    __shared__ float pool[64 * 65];      // 16.6 KB, unioned across roles
    const int f = flag[0];
    const int bx = blockIdx.x;
    if (bx < 512)
        gn_stats_dev(x, f, stats, bx, pool);
    else if (bx < 768)
        prep_t_dev(Wq, Wk, Wv, Wo, f, WkT, WqT, WvT, Wob, bx - 512, pool);
    else
        micro_raw_dev(Wq, Wk, Wo, bq, bk, bv, bo, f, w1, w2, b2, c0,
                      rowB, colB, bx - 768, pool);
}

// ---------------------------------------------------------------------------
// Legacy prep (fallback path): Wqk=[Wq;Wk], Wvb, Wob bf16; biases f32.
// ---------------------------------------------------------------------------
__global__ __launch_bounds__(256)
void prep_kernel(const void* __restrict__ Wq, const void* __restrict__ Wk,
                 const void* __restrict__ Wv, const void* __restrict__ Wo,
                 const void* __restrict__ bq, const void* __restrict__ bk,
                 const void* __restrict__ bv, const void* __restrict__ bo,
                 const int* __restrict__ flag,
                 bf16* __restrict__ Wqk, bf16* __restrict__ Wvb, bf16* __restrict__ Wob,
                 float* __restrict__ bQK, float* __restrict__ bV, float* __restrict__ bO)
{
    const int f = flag[0];
    const int idx = blockIdx.x * 256 + threadIdx.x;
    if (idx < 524288) {
        const int r = idx >> 9, c = idx & 511;
        float v = (r < 512) ? ldv(Wq, (long)r * 512 + c, f)
                            : ldv(Wk, (long)(r - 512) * 512 + c, f);
        Wqk[idx] = __float2bfloat16(v);
    } else if (idx < 786432) {
        Wvb[idx - 524288] = __float2bfloat16(ldv(Wv, idx - 524288, f));
    } else if (idx < 1048576) {
        Wob[idx - 786432] = __float2bfloat16(ldv(Wo, idx - 786432, f));
    } else {
        const int j = idx - 1048576;
        if      (j < 512)  bQK[j]        = ldv(bq, j, f);
        else if (j < 1024) bQK[j]        = ldv(bk, j - 512, f);
        else if (j < 1536) bV[j - 1024]  = ldv(bv, j - 1024, f);
        else if (j < 2048) bO[j - 1536]  = ldv(bo, j - 1536, f);
    }
}

// ---------------------------------------------------------------------------
// GN+SiLU with transpose INTO yx right half + fused uv partials (R9 proven).
// ---------------------------------------------------------------------------
__global__ __launch_bounds__(256)
void gn_apply_kernel(const void* __restrict__ x, const int* __restrict__ flag,
                     const float2* __restrict__ stats,
                     const void* __restrict__ gamma, const void* __restrict__ beta,
                     bf16* __restrict__ yx,
                     const float* __restrict__ w1, const float* __restrict__ w2,
                     float* __restrict__ rowB, float* __restrict__ colB,
                     float scale)
{
    const int f = flag[0];
    __shared__ float t[64][65];
    __shared__ float redu[4][64], redv[4][64];
    const int gx = gridDim.x, gy = gridDim.y;
    const int nwg = gx * gy * (int)gridDim.z;
    const int lin = blockIdx.x + gx * (blockIdx.y + gy * blockIdx.z);
    const int qq = nwg >> 3, rr = nwg & 7;
    const int xc = lin & 7, sq = lin >> 3;
    const int nl = (xc < rr ? xc * (qq + 1) : rr * (qq + 1) + (xc - rr) * qq) + sq;
    const int bxi = nl % gx;
    const int tt  = nl / gx;
    const int byi = tt % gy;
    const int bz  = tt / gy;

    const int i0 = bxi * 64;
    const int c0 = byi * 64;
    const int tid = threadIdx.x;
    const int il = tid & 63;
    const int hq = tid >> 6;              // 0..3
    float su = 0.f, sv = 0.f;
    #pragma unroll
    for (int r = 0; r < 16; ++r) {
        const int cl = r * 4 + hq;
        const int c = c0 + cl;
        const float2 st = stats[bz * NGROUP + (c >> 4)];
        const float ga = ldv(gamma, c, f), be = ldv(beta, c, f);
        float v = ldv(x, (long)bz * CCH * HWN + (long)c * HWN + i0 + il, f);
        v = (v - st.x) * st.y * ga + be;
        const float s = v / (1.f + __expf(-v));     // SiLU
        t[cl][il] = s;
        su += s * w1[c];
        sv += s * w2[c];
    }
    redu[hq][il] = su;
    redv[hq][il] = sv;
    __syncthreads();
    #pragma unroll
    for (int r = 0; r < 16; ++r) {
        const int ii = r * 4 + hq;
        yx[(long)bz * (HWN * (long)HWN) + (long)(i0 + ii) * 1024 + 512 + c0 + il] =
            __float2bfloat16(t[il][ii]);
    }
    if (tid < 64) {
        const float s1 = redu[0][tid] + redu[1][tid] + redu[2][tid] + redu[3][tid];
        const float s2 = redv[0][tid] + redv[1][tid] + redv[2][tid] + redv[3][tid];
        const long gi = (long)bz * HWN + i0 + tid;
        atomicAdd(&colB[gi], scale * s1);   // u-side -> colB
        atomicAdd(&rowB[gi], scale * s2);   // v-side -> rowB
    }
}

// legacy (fallback) gn: x -> xn [i][c], stride 512, per-batch
__global__ __launch_bounds__(256)
void gn_apply_old(const void* __restrict__ x, const int* __restrict__ flag,
                  const float2* __restrict__ stats,
                  const void* __restrict__ gamma, const void* __restrict__ beta,
                  bf16* __restrict__ xn, int zb)
{
    const int f = flag[0];
    __shared__ float t[64][65];
    const int bx = zb + blockIdx.z;
    const int i0 = blockIdx.x * 64;
    const int c0 = blockIdx.y * 64;
    const int tid = threadIdx.x;
    const int il = tid & 63;
    const int hq = tid >> 6;
    #pragma unroll
    for (int r = 0; r < 16; ++r) {
        const int cl = r * 4 + hq;
        const int c = c0 + cl;
        const float2 st = stats[bx * NGROUP + (c >> 4)];
        const float ga = ldv(gamma, c, f), be = ldv(beta, c, f);
        float v = ldv(x, (long)bx * CCH * HWN + (long)c * HWN + i0 + il, f);
        v = (v - st.x) * st.y * ga + be;
        t[cl][il] = v / (1.f + __expf(-v));
    }
    __syncthreads();
    #pragma unroll
    for (int r = 0; r < 16; ++r) {
        const int ii = r * 4 + hq;
        xn[(long)blockIdx.z * CCH * HWN + (long)(i0 + ii) * CCH + c0 + il] =
            __float2bfloat16(t[il][ii]);
    }
}

// ---------------------------------------------------------------------------
// MFMA TN GEMM device core (proven): C[m][n] = alpha*sum_k A[m][k]B[n][k].
// 128x128 tile, BK=32, 4 waves, glds16 dbuf + XOR swizzle.
// EXPS/RDIV/RDIVB/FINAL hooks + R7/R9 register prefetch of epilogue inputs.
// Block position (bxi,byi,bzi) supplied by the wrapper (swizzle done there).
// ---------------------------------------------------------------------------
template<bool FINAL, bool EXPS, bool RDIV, bool RDIVB>
__device__ __forceinline__
void gemm_dev(const bf16* __restrict__ A, const bf16* __restrict__ B,
              void* __restrict__ C, int K,
              int lda, int ldb, int ldc,
              long sA, long sB, long sC, int z0,
              const float* __restrict__ rowBias, long rbZ,
              const float* __restrict__ colBias, long cbZ,
              const float* __restrict__ cbase,
              float alpha, const void* __restrict__ resid, long sR,
              const int* __restrict__ flag,
              int bxi, int byi, int bzi)
{
    __shared__ bf16 lA[2][128 * 32];
    __shared__ bf16 lB[2][128 * 32];

    const int tid = threadIdx.x;
    const int w   = tid >> 6;
    const int l   = tid & 63;
    const int ln  = l & 15;
    const int qd  = l >> 4;
    const int wm  = (w >> 1) * 64;
    const int wn  = (w & 1) * 64;
    const int zA  = z0 + bzi;

    const bf16* Ab = A + (long)zA * sA;
    const bf16* Bb = B + (long)zA * sB;
    const int m0 = byi * 128;
    const int n0 = bxi * 128;

    const int sr   = l >> 2;
    const int kswz = ((l & 3) ^ ((l >> 3) & 3)) * 8;
    const bf16* gA0 = Ab + (long)(m0 + w * 16 + sr) * lda + kswz;
    const bf16* gA1 = gA0 + (long)64 * lda;
    const bf16* gB0 = Bb + (long)(n0 + w * 16 + sr) * ldb + kswz;
    const bf16* gB1 = gB0 + (long)64 * ldb;

    f32x4 acc[4][4];
    #pragma unroll
    for (int i = 0; i < 4; ++i)
        #pragma unroll
        for (int j = 0; j < 4; ++j)
            acc[i][j] = (f32x4){0.f, 0.f, 0.f, 0.f};

    f32x4 racc[4];
    #pragma unroll
    for (int i = 0; i < 4; ++i) racc[i] = (f32x4){0.f, 0.f, 0.f, 0.f};
    s16x8 ones;
    #pragma unroll
    for (int e = 0; e < 8; ++e) ones[e] = (short)0x3F80;   // bf16 1.0

    const int swA = (qd ^ ((ln >> 1) & 3)) * 8;

    glds16(gA0, &lA[0][w * 512]);
    glds16(gA1, &lA[0][2048 + w * 512]);
    glds16(gB0, &lB[0][w * 512]);
    glds16(gB1, &lB[0][2048 + w * 512]);

    // Prefetch all epilogue inputs into registers NOW (hide under K-loop).
    const int f = (FINAL && flag) ? flag[0] : 0;
    float rs[4][4][4];
    float rbv[4][4], cbv[4];
    float cba = 0.f;
    {
        if (rowBias) {
            #pragma unroll
            for (int i = 0; i < 4; ++i)
                #pragma unroll
                for (int r = 0; r < 4; ++r)
                    rbv[i][r] = rowBias[(long)zA * rbZ + m0 + wm + i * 16 + qd * 4 + r];
        }
        if (colBias) {
            #pragma unroll
            for (int j = 0; j < 4; ++j)
                cbv[j] = colBias[(long)zA * cbZ + n0 + wn + j * 16 + ln];
            if (cbase) cba = alpha * cbase[0];
        }
        if (FINAL && resid) {
            #pragma unroll
            for (int i = 0; i < 4; ++i)
                #pragma unroll
                for (int r = 0; r < 4; ++r) {
                    const int m = m0 + wm + i * 16 + qd * 4 + r;
                    #pragma unroll
                    for (int j = 0; j < 4; ++j) {
                        const int n = n0 + wn + j * 16 + ln;
                        rs[i][r][j] = ldv(resid, (long)zA * sR + (long)m * ldc + n, f);
                    }
                }
        }
        __builtin_amdgcn_sched_barrier(0);   // pin prefetch before the K-loop
    }

    const int NK = K >> 5;
    for (int t = 0; t < NK; ++t) {
        const int p = t & 1;
        __syncthreads();
        if (t + 1 < NK) {
            const int kk = (t + 1) << 5;
            glds16(gA0 + kk, &lA[p ^ 1][w * 512]);
            glds16(gA1 + kk, &lA[p ^ 1][2048 + w * 512]);
            glds16(gB0 + kk, &lB[p ^ 1][w * 512]);
            glds16(gB1 + kk, &lB[p ^ 1][2048 + w * 512]);
        }
        s16x8 af[4], bfr[4];
        #pragma unroll
        for (int i = 0; i < 4; ++i)
            af[i] = *(const s16x8*)&lA[p][(wm + i * 16 + ln) * 32 + swA];
        #pragma unroll
        for (int j = 0; j < 4; ++j)
            bfr[j] = *(const s16x8*)&lB[p][(wn + j * 16 + ln) * 32 + swA];
        if (RDIV) {
            #pragma unroll
            for (int i = 0; i < 4; ++i)
                racc[i] = __builtin_amdgcn_mfma_f32_16x16x32_bf16(
                    af[i], ones, racc[i], 0, 0, 0);
        }
        if (RDIVB) {
            #pragma unroll
            for (int j = 0; j < 4; ++j)
                racc[j] = __builtin_amdgcn_mfma_f32_16x16x32_bf16(
                    ones, bfr[j], racc[j], 0, 0, 0);
        }
        #pragma unroll
        for (int i = 0; i < 4; ++i)
            #pragma unroll
            for (int j = 0; j < 4; ++j)
                acc[i][j] = __builtin_amdgcn_mfma_f32_16x16x32_bf16(
                    af[i], bfr[j], acc[i][j], 0, 0, 0);
    }

    float invb[4];
    if (RDIVB) {
        #pragma unroll
        for (int j = 0; j < 4; ++j) invb[j] = 1.f / racc[j][0];
    }

    // epilogue: C/D layout col = lane&15, row = qd*4 + reg  [m89]
    #pragma unroll
    for (int i = 0; i < 4; ++i) {
        #pragma unroll
        for (int r = 0; r < 4; ++r) {
            const int m = m0 + wm + i * 16 + qd * 4 + r;
            const float rb = rowBias ? rbv[i][r] : 0.f;
            const float inv = RDIV ? (1.f / racc[i][r]) : 1.f;
            #pragma unroll
            for (int j = 0; j < 4; ++j) {
                const int n = n0 + wn + j * 16 + ln;
                float v = alpha * acc[i][j][r] + rb;
                if (colBias) v += cbv[j] + cba;
                if (EXPS) v = __expf(fminf(v, 60.f));
                if (RDIV) v *= inv;
                if (RDIVB) v *= invb[j];
                const long idx = (long)zA * sC + (long)m * ldc + n;
                if (FINAL) {
                    if (resid) v += rs[i][r][j];
                    stv(C, idx, f, v);
                } else {
                    ((bf16*)C)[idx] = __float2bfloat16(v);
                }
            }
        }
    }
}

// standalone GEMM kernel: 3D grid + XCD-bijective swizzle (m204)
template<bool FINAL, bool EXPS, bool RDIV, bool RDIVB>
__global__ __launch_bounds__(256)
void mfma_gemm(const bf16* __restrict__ A, const bf16* __restrict__ B,
               void* __restrict__ C, int K,
               int lda, int ldb, int ldc,
               long sA, long sB, long sC, int z0,
               const float* __restrict__ rowBias, long rbZ,
               const float* __restrict__ colBias, long cbZ,
               const float* __restrict__ cbase,
               float alpha, const void* __restrict__ resid, long sR,
               const int* __restrict__ flag)
{
    const int gx = gridDim.x, gy = gridDim.y;
    const int nwg = gx * gy * (int)gridDim.z;
    const int lin = blockIdx.x + gx * (blockIdx.y + gy * blockIdx.z);
    const int qq = nwg >> 3, rr = nwg & 7;
    const int xc = lin & 7, sq = lin >> 3;
    const int nl = (xc < rr ? xc * (qq + 1) : rr * (qq + 1) + (xc - rr) * qq) + sq;
    const int bxi = nl % gx;
    const int tt  = nl / gx;
    const int byi = tt % gy;
    const int bzi = tt / gy;
    gemm_dev<FINAL, EXPS, RDIV, RDIVB>(A, B, C, K, lda, ldb, ldc, sA, sB, sC, z0,
                                       rowBias, rbZ, colBias, cbZ, cbase, alpha,
                                       resid, sR, flag, bxi, byi, bzi);
}

// ---------------------------------------------------------------------------
// Dual GEMM (R10): two independent plain GEMMs in ONE launch (concurrency for
// grids too small to fill the chip). Blocks [0,a.nblk) run A; rest run B.
// ---------------------------------------------------------------------------
struct GemmP {
    const bf16* A; const bf16* B; void* C;
    int K, lda, ldb, ldc;
    long sA, sB, sC;
    const float* rowBias; long rbZ;
    int gx, gy, nblk;
};

__global__ __launch_bounds__(256)
void dual_gemm_kernel(GemmP a, GemmP b)
{
    const int lin = blockIdx.x;
    const GemmP& p = (lin < a.nblk) ? a : b;
    const int sub  = (lin < a.nblk) ? lin : lin - a.nblk;
    const int nwg = p.nblk;
    const int qq = nwg >> 3, rr = nwg & 7;
    const int xc = sub & 7, sq = sub >> 3;
    const int nl = (xc < rr ? xc * (qq + 1) : rr * (qq + 1) + (xc - rr) * qq) + sq;
    const int bxi = nl % p.gx;
    const int tt  = nl / p.gx;
    const int byi = tt % p.gy;
    const int bzi = tt / p.gy;
    gemm_dev<false, false, false, false>(p.A, p.B, p.C, p.K, p.lda, p.ldb, p.ldc,
                                         p.sA, p.sB, p.sC, 0,
                                         p.rowBias, p.rbZ, nullptr, 0L, nullptr,
                                         1.f, nullptr, 0L, nullptr, bxi, byi, bzi);
}

// ---------------------------------------------------------------------------
extern "C" void kernel_launch(void* const* d_in, const int* in_sizes, int n_in,
                              void* d_out, int out_size, void* d_ws, size_t ws_size,
                              hipStream_t stream)
{
    const long NX = (long)NBATCH * CCH * HWN;
    int ix, iWq, ibq, iWk, ibk, iWv, ibv, iWo, ibo, iga, ibe;
    if (in_sizes[0] == NX) {
        ix = 0; iWq = 1; ibq = 2; iWk = 3; ibk = 4; iWv = 5; ibv = 6;
        iWo = 7; ibo = 8; iga = 9; ibe = 10;
    } else {
        iWk = 0; iWo = 1; iWq = 2; iWv = 3; ibe = 4; ibk = 5; ibo = 6;
        ibq = 7; ibv = 8; iga = 9; ix = 10;
    }
    const void* x     = d_in[ix];
    const void* Wq    = d_in[iWq];
    const void* bq    = d_in[ibq];
    const void* Wk    = d_in[iWk];
    const void* bk    = d_in[ibk];
    const void* Wv    = d_in[iWv];
    const void* bv    = d_in[ibv];
    const void* Wo    = d_in[iWo];
    const void* bo    = d_in[ibo];
    const void* gamma = d_in[iga];
    const void* beta  = d_in[ibe];

    const long CHW = (long)CCH * HWN;      // 524288
    const long NN  = (long)HWN * HWN;      // 1048576
    const size_t MB = 1ull << 20;
    const size_t KB = 1024;
    char* ws = (char*)d_ws;

    dim3 blk(256);
    const float scale = 0.044194173824159216f;   // 512^-0.5
    const float* FNUL = nullptr;
    const void*  VNUL = nullptr;

    if (ws_size >= 84 * MB) {
        // ---- associativity pipeline, dependency-compacted (R10) ----
        bf16* WkT = (bf16*)ws;                       // A z0
        bf16* Wob = (bf16*)(ws + 512 * KB);          // A z1
        bf16* WqT = (bf16*)(ws + MB);                // B z0
        bf16* WvT = (bf16*)(ws + MB + 512 * KB);     // B z1
        bf16* Mt  = (bf16*)(ws + 2 * MB);            // C z0 : Wk^T Wq
        bf16* W2  = (bf16*)(ws + 2 * MB + 512 * KB); // C z1 : Wo Wv
        float*  w1   = (float*)(ws + 3 * MB + 8 * KB);
        float*  w2   = (float*)(ws + 3 * MB + 10 * KB);
        float*  b2   = (float*)(ws + 3 * MB + 12 * KB);
        float*  c0   = (float*)(ws + 3 * MB + 14 * KB);
        float2* stats= (float2*)(ws + 3 * MB + 16 * KB);   // 4 KB
        int*    flag = (int*)(ws + 3 * MB + 20 * KB);
        float*  rowB = (float*)(ws + 3 * MB + 24 * KB);    // 64 KB
        float*  colB = (float*)(ws + 3 * MB + 88 * KB);    // 64 KB
        bf16* Zt = (bf16*)(ws + 4 * MB);             // 16 MB [b][c][j]
        bf16* S  = (bf16*)(ws + 20 * MB);            // 32 MB [b][i][j]
        bf16* yx = (bf16*)(ws + 52 * MB);            // 32 MB [b][i][1024]: y|xn

        detect_kernel<<<dim3(1), blk, 0, stream>>>(x, flag);
        // MEGA1: gn_stats(512) || prep_t(256) || micro_raw+zero(9)
        mega1_kernel<<<dim3(777), blk, 0, stream>>>(
            x, flag, stats, Wq, Wk, Wv, Wo, bq, bk, bv, bo,
            WkT, WqT, WvT, Wob, w1, w2, b2, c0, rowB, colB);
        // z=0: Mt = Wk^T Wq ; z=1: W2 = Wo Wv
        mfma_gemm<false, false, false, false><<<dim3(4, 4, 2), blk, 0, stream>>>(
            WkT, WqT, Mt, 512, 512, 512, 512, 262144L, 262144L, 262144L, 0,
            FNUL, 0L, FNUL, 0L, FNUL, 1.f, VNUL, 0L, nullptr);
        // gn(x)+SiLU -> yx[:,512:1024]; fused uv partials -> rowB/colB
        gn_apply_kernel<<<dim3(16, 8, NBATCH), blk, 0, stream>>>(
            x, flag, stats, gamma, beta, yx, w1, w2, rowB, colB, scale);
        // DUAL: y = xn@Mt^T -> yx[:,0:512]  ||  Zt = W2@xn^T + b2
        {
            GemmP py, pz;
            py.A = yx + 512; py.B = Mt; py.C = yx;
            py.K = 512; py.lda = 1024; py.ldb = 512; py.ldc = 1024;
            py.sA = 0L; py.sB = 0L; py.sC = 0L;
            py.rowBias = nullptr; py.rbZ = 0L;
            py.gx = 4; py.gy = 128; py.nblk = 512;
            pz.A = W2; pz.B = yx + 512; pz.C = Zt;
            pz.K = 512; pz.lda = 512; pz.ldb = 1024; pz.ldc = 1024;
            pz.sA = 0L; pz.sB = NN; pz.sC = CHW;
            pz.rowBias = b2; pz.rbZ = 0L;
            pz.gx = 8; pz.gy = 4; pz.nblk = 512;
            dual_gemm_kernel<<<dim3(1024), blk, 0, stream>>>(py, pz);
        }
        // S = exp(scale*(y.xn^T) + rowB_i + colB_j + scale*c0)
        mfma_gemm<false, true, false, false><<<dim3(8, 8, NBATCH), blk, 0, stream>>>(
            yx, yx + 512, S, 512, 1024, 1024, 1024, NN, NN, NN, 0,
            rowB, 1024L, colB, 1024L, c0, scale, VNUL, 0L, nullptr);
        // out[c][i] = (Zt . S^T) / rowsum(S_i) + x
        mfma_gemm<true, false, false, true><<<dim3(8, 4, NBATCH), blk, 0, stream>>>(
            Zt, S, d_out, 1024, 1024, 1024, 1024, CHW, NN, CHW, 0,
            FNUL, 0L, FNUL, 0L, FNUL, 1.f, x, CHW, flag);
    } else {
        // ---- legacy per-batch fallback (ws >= 9 MB) ----
        bf16*   Wqk   = (bf16*)ws;                         // 1 MB
        bf16*   Wvb   = (bf16*)(ws + MB);                  // 0.5 MB
        bf16*   Wob   = (bf16*)(ws + MB + MB / 2);         // 0.5 MB
        float*  bQK   = (float*)(ws + 2 * MB);
        float*  bV    = (float*)(ws + 2 * MB + 4096);
        float*  bO    = (float*)(ws + 2 * MB + 6144);
        float2* stats = (float2*)(ws + 2 * MB + 8192);
        int*    flag  = (int*)(ws + 2 * MB + 12288);
        bf16* xn = (bf16*)(ws + 3 * MB);      // 1 MB
        bf16* V  = (bf16*)(ws + 4 * MB);      // 1 MB
        bf16* QK = (bf16*)(ws + 5 * MB);      // 2 MB
        bf16* S  = (bf16*)(ws + 7 * MB);      // 2 MB
        bf16* O  = xn;

        detect_kernel<<<dim3(1), blk, 0, stream>>>(x, flag);
        // stats via mega1's gn_stats path is merged-only; reuse standalone body:
        mega1_kernel<<<dim3(512), blk, 0, stream>>>(
            x, flag, stats, Wq, Wk, Wv, Wo, bq, bk, bv, bo,
            nullptr, nullptr, nullptr, nullptr,
            nullptr, nullptr, nullptr, nullptr, nullptr, nullptr);
        prep_kernel<<<dim3(4104), blk, 0, stream>>>(Wq, Wk, Wv, Wo, bq, bk, bv, bo,
                                                    flag, Wqk, Wvb, Wob, bQK, bV, bO);
        for (int b = 0; b < NBATCH; ++b) {
            gn_apply_old<<<dim3(16, 8, 1), blk, 0, stream>>>(
                x, flag, stats, gamma, beta, xn, b);
            mfma_gemm<false, false, false, false><<<dim3(8, 8, 1), blk, 0, stream>>>(
                xn, Wqk, QK, 512, 512, 512, 1024, 0L, 0L, 0L, 0,
                FNUL, 0L, bQK, 0L, FNUL, 1.f, VNUL, 0L, nullptr);
            mfma_gemm<false, false, false, false><<<dim3(8, 4, 1), blk, 0, stream>>>(
                Wvb, xn, V, 512, 512, 512, 1024, 0L, 0L, 0L, 0,
                bV, 0L, FNUL, 0L, FNUL, 1.f, VNUL, 0L, nullptr);
            mfma_gemm<false, true, false, false><<<dim3(8, 8, 1), blk, 0, stream>>>(
                QK, QK + 512, S, 512, 1024, 1024, 1024, 0L, 0L, 0L, b,
                FNUL, 0L, FNUL, 0L, FNUL, scale, VNUL, 0L, nullptr);
            mfma_gemm<false, false, true, false><<<dim3(4, 8, 1), blk, 0, stream>>>(
                S, V, O, 1024, 1024, 1024, 512, 0L, 0L, 0L, b,
                FNUL, 0L, FNUL, 0L, FNUL, 1.f, VNUL, 0L, nullptr);
            mfma_gemm<true, false, false, false><<<dim3(8, 4, 1), blk, 0, stream>>>(
                Wob, O, d_out, 512, 512, 512, 1024, 0L, 0L, CHW, b,
                bO, 0L, FNUL, 0L, FNUL, 1.f, x, CHW, flag);
        }
    }
}

// Round 12
// 237.759 us; speedup vs baseline: 1.1694x; 1.1694x over previous
//
#include <hip/hip_runtime.h>
#include <hip/hip_bf16.h>

#define HWN    1024
#define CCH    512
#define NBATCH 16
#define NGROUP 32
#define EPSV   1e-5f

using bf16 = __hip_bfloat16;
typedef __attribute__((ext_vector_type(4))) float f32x4;
typedef __attribute__((ext_vector_type(8))) short s16x8;

__device__ __forceinline__ float ldv(const void* p, long i, int c) {
    return c ? ((const float*)p)[i] : __bfloat162float(((const bf16*)p)[i]);
}
__device__ __forceinline__ void stv(void* p, long i, int c, float v) {
    if (c) ((float*)p)[i] = v;
    else   ((bf16*)p)[i]  = __float2bfloat16(v);
}
__device__ __forceinline__ float b2f(short s) {
    return __uint_as_float(((unsigned)(unsigned short)s) << 16);
}

// async global->LDS, 16B per lane; lds dest = wave-uniform base + lane*16
__device__ __forceinline__ void glds16(const void* g, void* l) {
    __builtin_amdgcn_global_load_lds(
        (const __attribute__((address_space(1))) void*)g,
        (__attribute__((address_space(3))) void*)l, 16, 0, 0);
}

// ---------------------------------------------------------------------------
// Storage dtype detector. flag=1 => fp32 storage.
// ---------------------------------------------------------------------------
__global__ __launch_bounds__(256) void detect_kernel(const void* __restrict__ x,
                                                     int* __restrict__ flag)
{
    const int tid = threadIdx.x;
    const unsigned short* h = (const unsigned short*)x;
    int ok = 0;
    for (int i = tid; i < 4096; i += 256) {
        int e = (h[2 * i] >> 7) & 0xFF;
        if (e >= 100 && e <= 135) ok++;
    }
    __shared__ int red[256];
    red[tid] = ok; __syncthreads();
    for (int off = 128; off > 0; off >>= 1) {
        if (tid < off) red[tid] += red[tid + off];
        __syncthreads();
    }
    if (tid == 0) flag[0] = (red[0] < 2458) ? 1 : 0;
}

// ---------------------------------------------------------------------------
// MEGA1 (R11): ONLY the proven-fast flag-dependent bodies merged:
//   [0,512)   gn_stats   (R4-proven body)
//   [512,768) prep_t     (transposes + vectorized Wo copy, R6-proven)
//   768,769   zero rowB/colB (replaces memset)
// R10's micro_raw (512 serial scalar loads w/ runtime-dtype branch) caused a
// 66us latency tail — micro reverted to the vectorized post-prep_t form.
// ---------------------------------------------------------------------------
__device__ __forceinline__
void gn_stats_dev(const void* __restrict__ x, int f, float2* __restrict__ stats,
                  int bidx, float* pool)
{
    const int b = bidx >> 5, g = bidx & 31;
    const long base = ((long)b * CCH + (long)g * (CCH / NGROUP)) * HWN;
    const int tid = threadIdx.x;
    const int n = (CCH / NGROUP) * HWN;       // 16384
    float s = 0.f, ss = 0.f;
    if (f) {
        const float4* xp = (const float4*)((const float*)x + base);
        #pragma unroll
        for (int k = 0; k < 16; ++k) {
            float4 u = xp[tid + k * 256];
            s  += u.x + u.y + u.z + u.w;
            ss += u.x * u.x + u.y * u.y + u.z * u.z + u.w * u.w;
        }
    } else {
        for (int i = tid; i < n; i += 256) {
            float v = ldv(x, base + i, 0);
            s += v; ss += v * v;
        }
    }
    float* r1 = pool;
    float* r2 = pool + 256;
    r1[tid] = s; r2[tid] = ss; __syncthreads();
    for (int off = 128; off > 0; off >>= 1) {
        if (tid < off) { r1[tid] += r1[tid + off]; r2[tid] += r2[tid + off]; }
        __syncthreads();
    }
    if (tid == 0) {
        float mean = r1[0] / n;
        float var  = r2[0] / n - mean * mean;
        stats[bidx] = make_float2(mean, rsqrtf(var + EPSV));
    }
}

__device__ __forceinline__
void prep_t_dev(const void* __restrict__ Wq, const void* __restrict__ Wk,
                const void* __restrict__ Wv, const void* __restrict__ Wo,
                int f, bf16* __restrict__ WkT, bf16* __restrict__ WqT,
                bf16* __restrict__ WvT, bf16* __restrict__ Wob,
                int idx, float* pool)
{
    const int tid = threadIdx.x;
    if (idx < 192) {
        const int mat = idx >> 6;           // 0:Wq->WqT 1:Wk->WkT 2:Wv->WvT
        const void* src = mat == 0 ? Wq : mat == 1 ? Wk : Wv;
        bf16* dst = mat == 0 ? WqT : mat == 1 ? WkT : WvT;
        const int tile = idx & 63;
        const int r0 = (tile >> 3) * 64, c0 = (tile & 7) * 64;
        const int il = tid & 63, hq = tid >> 6;
        #pragma unroll
        for (int rr = 0; rr < 16; ++rr) {
            const int r = rr * 4 + hq;
            pool[r * 65 + il] = ldv(src, (long)(r0 + r) * 512 + c0 + il, f);
        }
        __syncthreads();
        #pragma unroll
        for (int rr = 0; rr < 16; ++rr) {
            const int cc = rr * 4 + hq;
            dst[(long)(c0 + cc) * 512 + r0 + il] = __float2bfloat16(pool[il * 65 + cc]);
        }
    } else {
        // Wo copy: 64 blocks x 4096 elems; 8-elem vector chunks per thread.
        const int base = (idx - 192) * 4096;
        #pragma unroll
        for (int pass = 0; pass < 2; ++pass) {
            const int i = base + pass * 2048 + tid * 8;
            s16x8 out;
            if (f) {
                const float4* sp = (const float4*)Wo;
                const float4 a = sp[i >> 2];
                const float4 b = sp[(i >> 2) + 1];
                out[0] = (short)(ushort)__bfloat16_as_ushort(__float2bfloat16(a.x));
                out[1] = (short)(ushort)__bfloat16_as_ushort(__float2bfloat16(a.y));
                out[2] = (short)(ushort)__bfloat16_as_ushort(__float2bfloat16(a.z));
                out[3] = (short)(ushort)__bfloat16_as_ushort(__float2bfloat16(a.w));
                out[4] = (short)(ushort)__bfloat16_as_ushort(__float2bfloat16(b.x));
                out[5] = (short)(ushort)__bfloat16_as_ushort(__float2bfloat16(b.y));
                out[6] = (short)(ushort)__bfloat16_as_ushort(__float2bfloat16(b.z));
                out[7] = (short)(ushort)__bfloat16_as_ushort(__float2bfloat16(b.w));
            } else {
                out = *(const s16x8*)((const bf16*)Wo + i);
            }
            *(s16x8*)&Wob[i] = out;
        }
    }
}

__global__ __launch_bounds__(256)
void mega1_kernel(const void* __restrict__ x, const int* __restrict__ flag,
                  float2* __restrict__ stats,
                  const void* __restrict__ Wq, const void* __restrict__ Wk,
                  const void* __restrict__ Wv, const void* __restrict__ Wo,
                  bf16* __restrict__ WkT, bf16* __restrict__ WqT,
                  bf16* __restrict__ WvT, bf16* __restrict__ Wob,
                  float* __restrict__ rowB, float* __restrict__ colB)
{
    __shared__ float pool[64 * 65];      // 16.6 KB, unioned across roles
    const int f = flag[0];
    const int bx = blockIdx.x;
    if (bx < 512)
        gn_stats_dev(x, f, stats, bx, pool);
    else if (bx < 768)
        prep_t_dev(Wq, Wk, Wv, Wo, f, WkT, WqT, WvT, Wob, bx - 512, pool);
    else {
        float4* d4 = (float4*)((bx == 768) ? rowB : colB);
        for (int i = threadIdx.x; i < 4096; i += 256)
            d4[i] = make_float4(0.f, 0.f, 0.f, 0.f);
    }
}

// ---------------------------------------------------------------------------
// micro (R9-proven vectorized form): w1 = Wk^T bq, w2 = Wq^T bk,
// b2 = Wo bv + bo, c0 = bq.bk — rows of WkT/WqT/Wob are the dot vectors.
// Biases read raw via ldv (2 setup loads/thread, not in the hot loop).
// ---------------------------------------------------------------------------
__global__ __launch_bounds__(256)
void micro_kernel(const bf16* __restrict__ WkT, const bf16* __restrict__ WqT,
                  const bf16* __restrict__ Wob,
                  const void* __restrict__ bq, const void* __restrict__ bk,
                  const void* __restrict__ bv, const void* __restrict__ bo,
                  const int* __restrict__ flag,
                  float* __restrict__ w1, float* __restrict__ w2,
                  float* __restrict__ b2, float* __restrict__ c0)
{
    const int f = flag[0];
    const int bx = blockIdx.x, tid = threadIdx.x;
    if (bx < 6) {
        __shared__ float vec[512];
        const void* bsrc = bx < 2 ? bq : bx < 4 ? bk : bv;
        const bf16* msrc = bx < 2 ? WkT : bx < 4 ? WqT : Wob;
        for (int i = tid; i < 512; i += 256) vec[i] = ldv(bsrc, i, f);
        __syncthreads();
        const int o = (bx & 1) * 256 + tid;
        const bf16* row = msrc + (long)o * 512;
        float s = 0.f;
        for (int k = 0; k < 512; k += 8) {
            s16x8 v = *(const s16x8*)&row[k];
            #pragma unroll
            for (int e = 0; e < 8; ++e) s += b2f(v[e]) * vec[k + e];
        }
        if (bx < 2)      w1[o] = s;
        else if (bx < 4) w2[o] = s;
        else             b2[o] = s + ldv(bo, o, f);
    } else {
        __shared__ float red[256];
        red[tid] = ldv(bq, tid, f) * ldv(bk, tid, f)
                 + ldv(bq, tid + 256, f) * ldv(bk, tid + 256, f);
        __syncthreads();
        for (int off = 128; off > 0; off >>= 1) {
            if (tid < off) red[tid] += red[tid + off];
            __syncthreads();
        }
        if (tid == 0) c0[0] = red[0];
    }
}

// ---------------------------------------------------------------------------
// Legacy prep (fallback path): Wqk=[Wq;Wk], Wvb, Wob bf16; biases f32.
// ---------------------------------------------------------------------------
__global__ __launch_bounds__(256)
void prep_kernel(const void* __restrict__ Wq, const void* __restrict__ Wk,
                 const void* __restrict__ Wv, const void* __restrict__ Wo,
                 const void* __restrict__ bq, const void* __restrict__ bk,
                 const void* __restrict__ bv, const void* __restrict__ bo,
                 const int* __restrict__ flag,
                 bf16* __restrict__ Wqk, bf16* __restrict__ Wvb, bf16* __restrict__ Wob,
                 float* __restrict__ bQK, float* __restrict__ bV, float* __restrict__ bO)
{
    const int f = flag[0];
    const int idx = blockIdx.x * 256 + threadIdx.x;
    if (idx < 524288) {
        const int r = idx >> 9, c = idx & 511;
        float v = (r < 512) ? ldv(Wq, (long)r * 512 + c, f)
                            : ldv(Wk, (long)(r - 512) * 512 + c, f);
        Wqk[idx] = __float2bfloat16(v);
    } else if (idx < 786432) {
        Wvb[idx - 524288] = __float2bfloat16(ldv(Wv, idx - 524288, f));
    } else if (idx < 1048576) {
        Wob[idx - 786432] = __float2bfloat16(ldv(Wo, idx - 786432, f));
    } else {
        const int j = idx - 1048576;
        if      (j < 512)  bQK[j]        = ldv(bq, j, f);
        else if (j < 1024) bQK[j]        = ldv(bk, j - 512, f);
        else if (j < 1536) bV[j - 1024]  = ldv(bv, j - 1024, f);
        else if (j < 2048) bO[j - 1536]  = ldv(bo, j - 1536, f);
    }
}

// ---------------------------------------------------------------------------
// GN+SiLU with transpose INTO yx right half + fused uv partials (R9 proven).
// ---------------------------------------------------------------------------
__global__ __launch_bounds__(256)
void gn_apply_kernel(const void* __restrict__ x, const int* __restrict__ flag,
                     const float2* __restrict__ stats,
                     const void* __restrict__ gamma, const void* __restrict__ beta,
                     bf16* __restrict__ yx,
                     const float* __restrict__ w1, const float* __restrict__ w2,
                     float* __restrict__ rowB, float* __restrict__ colB,
                     float scale)
{
    const int f = flag[0];
    __shared__ float t[64][65];
    __shared__ float redu[4][64], redv[4][64];
    const int gx = gridDim.x, gy = gridDim.y;
    const int nwg = gx * gy * (int)gridDim.z;
    const int lin = blockIdx.x + gx * (blockIdx.y + gy * blockIdx.z);
    const int qq = nwg >> 3, rr = nwg & 7;
    const int xc = lin & 7, sq = lin >> 3;
    const int nl = (xc < rr ? xc * (qq + 1) : rr * (qq + 1) + (xc - rr) * qq) + sq;
    const int bxi = nl % gx;
    const int tt  = nl / gx;
    const int byi = tt % gy;
    const int bz  = tt / gy;

    const int i0 = bxi * 64;
    const int c0 = byi * 64;
    const int tid = threadIdx.x;
    const int il = tid & 63;
    const int hq = tid >> 6;              // 0..3
    float su = 0.f, sv = 0.f;
    #pragma unroll
    for (int r = 0; r < 16; ++r) {
        const int cl = r * 4 + hq;
        const int c = c0 + cl;
        const float2 st = stats[bz * NGROUP + (c >> 4)];
        const float ga = ldv(gamma, c, f), be = ldv(beta, c, f);
        float v = ldv(x, (long)bz * CCH * HWN + (long)c * HWN + i0 + il, f);
        v = (v - st.x) * st.y * ga + be;
        const float s = v / (1.f + __expf(-v));     // SiLU
        t[cl][il] = s;
        su += s * w1[c];
        sv += s * w2[c];
    }
    redu[hq][il] = su;
    redv[hq][il] = sv;
    __syncthreads();
    #pragma unroll
    for (int r = 0; r < 16; ++r) {
        const int ii = r * 4 + hq;
        yx[(long)bz * (HWN * (long)HWN) + (long)(i0 + ii) * 1024 + 512 + c0 + il] =
            __float2bfloat16(t[il][ii]);
    }
    if (tid < 64) {
        const float s1 = redu[0][tid] + redu[1][tid] + redu[2][tid] + redu[3][tid];
        const float s2 = redv[0][tid] + redv[1][tid] + redv[2][tid] + redv[3][tid];
        const long gi = (long)bz * HWN + i0 + tid;
        atomicAdd(&colB[gi], scale * s1);   // u-side -> colB
        atomicAdd(&rowB[gi], scale * s2);   // v-side -> rowB
    }
}

// legacy (fallback) gn: x -> xn [i][c], stride 512, per-batch
__global__ __launch_bounds__(256)
void gn_apply_old(const void* __restrict__ x, const int* __restrict__ flag,
                  const float2* __restrict__ stats,
                  const void* __restrict__ gamma, const void* __restrict__ beta,
                  bf16* __restrict__ xn, int zb)
{
    const int f = flag[0];
    __shared__ float t[64][65];
    const int bx = zb + blockIdx.z;
    const int i0 = blockIdx.x * 64;
    const int c0 = blockIdx.y * 64;
    const int tid = threadIdx.x;
    const int il = tid & 63;
    const int hq = tid >> 6;
    #pragma unroll
    for (int r = 0; r < 16; ++r) {
        const int cl = r * 4 + hq;
        const int c = c0 + cl;
        const float2 st = stats[bx * NGROUP + (c >> 4)];
        const float ga = ldv(gamma, c, f), be = ldv(beta, c, f);
        float v = ldv(x, (long)bx * CCH * HWN + (long)c * HWN + i0 + il, f);
        v = (v - st.x) * st.y * ga + be;
        t[cl][il] = v / (1.f + __expf(-v));
    }
    __syncthreads();
    #pragma unroll
    for (int r = 0; r < 16; ++r) {
        const int ii = r * 4 + hq;
        xn[(long)blockIdx.z * CCH * HWN + (long)(i0 + ii) * CCH + c0 + il] =
            __float2bfloat16(t[il][ii]);
    }
}

// ---------------------------------------------------------------------------
// MFMA TN GEMM device core (proven): C[m][n] = alpha*sum_k A[m][k]B[n][k].
// 128x128 tile, BK=32, 4 waves, glds16 dbuf + XOR swizzle.
// EXPS/RDIV/RDIVB/FINAL hooks + R7/R9 register prefetch of epilogue inputs.
// ---------------------------------------------------------------------------
template<bool FINAL, bool EXPS, bool RDIV, bool RDIVB>
__device__ __forceinline__
void gemm_dev(const bf16* __restrict__ A, const bf16* __restrict__ B,
              void* __restrict__ C, int K,
              int lda, int ldb, int ldc,
              long sA, long sB, long sC, int z0,
              const float* __restrict__ rowBias, long rbZ,
              const float* __restrict__ colBias, long cbZ,
              const float* __restrict__ cbase,
              float alpha, const void* __restrict__ resid, long sR,
              const int* __restrict__ flag,
              int bxi, int byi, int bzi)
{
    __shared__ bf16 lA[2][128 * 32];
    __shared__ bf16 lB[2][128 * 32];

    const int tid = threadIdx.x;
    const int w   = tid >> 6;
    const int l   = tid & 63;
    const int ln  = l & 15;
    const int qd  = l >> 4;
    const int wm  = (w >> 1) * 64;
    const int wn  = (w & 1) * 64;
    const int zA  = z0 + bzi;

    const bf16* Ab = A + (long)zA * sA;
    const bf16* Bb = B + (long)zA * sB;
    const int m0 = byi * 128;
    const int n0 = bxi * 128;

    const int sr   = l >> 2;
    const int kswz = ((l & 3) ^ ((l >> 3) & 3)) * 8;
    const bf16* gA0 = Ab + (long)(m0 + w * 16 + sr) * lda + kswz;
    const bf16* gA1 = gA0 + (long)64 * lda;
    const bf16* gB0 = Bb + (long)(n0 + w * 16 + sr) * ldb + kswz;
    const bf16* gB1 = gB0 + (long)64 * ldb;

    f32x4 acc[4][4];
    #pragma unroll
    for (int i = 0; i < 4; ++i)
        #pragma unroll
        for (int j = 0; j < 4; ++j)
            acc[i][j] = (f32x4){0.f, 0.f, 0.f, 0.f};

    f32x4 racc[4];
    #pragma unroll
    for (int i = 0; i < 4; ++i) racc[i] = (f32x4){0.f, 0.f, 0.f, 0.f};
    s16x8 ones;
    #pragma unroll
    for (int e = 0; e < 8; ++e) ones[e] = (short)0x3F80;   // bf16 1.0

    const int swA = (qd ^ ((ln >> 1) & 3)) * 8;

    glds16(gA0, &lA[0][w * 512]);
    glds16(gA1, &lA[0][2048 + w * 512]);
    glds16(gB0, &lB[0][w * 512]);
    glds16(gB1, &lB[0][2048 + w * 512]);

    // Prefetch all epilogue inputs into registers NOW (hide under K-loop).
    const int f = (FINAL && flag) ? flag[0] : 0;
    float rs[4][4][4];
    float rbv[4][4], cbv[4];
    float cba = 0.f;
    {
        if (rowBias) {
            #pragma unroll
            for (int i = 0; i < 4; ++i)
                #pragma unroll
                for (int r = 0; r < 4; ++r)
                    rbv[i][r] = rowBias[(long)zA * rbZ + m0 + wm + i * 16 + qd * 4 + r];
        }
        if (colBias) {
            #pragma unroll
            for (int j = 0; j < 4; ++j)
                cbv[j] = colBias[(long)zA * cbZ + n0 + wn + j * 16 + ln];
            if (cbase) cba = alpha * cbase[0];
        }
        if (FINAL && resid) {
            #pragma unroll
            for (int i = 0; i < 4; ++i)
                #pragma unroll
                for (int r = 0; r < 4; ++r) {
                    const int m = m0 + wm + i * 16 + qd * 4 + r;
                    #pragma unroll
                    for (int j = 0; j < 4; ++j) {
                        const int n = n0 + wn + j * 16 + ln;
                        rs[i][r][j] = ldv(resid, (long)zA * sR + (long)m * ldc + n, f);
                    }
                }
        }
        __builtin_amdgcn_sched_barrier(0);   // pin prefetch before the K-loop
    }

    const int NK = K >> 5;
    for (int t = 0; t < NK; ++t) {
        const int p = t & 1;
        __syncthreads();
        if (t + 1 < NK) {
            const int kk = (t + 1) << 5;
            glds16(gA0 + kk, &lA[p ^ 1][w * 512]);
            glds16(gA1 + kk, &lA[p ^ 1][2048 + w * 512]);
            glds16(gB0 + kk, &lB[p ^ 1][w * 512]);
            glds16(gB1 + kk, &lB[p ^ 1][2048 + w * 512]);
        }
        s16x8 af[4], bfr[4];
        #pragma unroll
        for (int i = 0; i < 4; ++i)
            af[i] = *(const s16x8*)&lA[p][(wm + i * 16 + ln) * 32 + swA];
        #pragma unroll
        for (int j = 0; j < 4; ++j)
            bfr[j] = *(const s16x8*)&lB[p][(wn + j * 16 + ln) * 32 + swA];
        if (RDIV) {
            #pragma unroll
            for (int i = 0; i < 4; ++i)
                racc[i] = __builtin_amdgcn_mfma_f32_16x16x32_bf16(
                    af[i], ones, racc[i], 0, 0, 0);
        }
        if (RDIVB) {
            #pragma unroll
            for (int j = 0; j < 4; ++j)
                racc[j] = __builtin_amdgcn_mfma_f32_16x16x32_bf16(
                    ones, bfr[j], racc[j], 0, 0, 0);
        }
        #pragma unroll
        for (int i = 0; i < 4; ++i)
            #pragma unroll
            for (int j = 0; j < 4; ++j)
                acc[i][j] = __builtin_amdgcn_mfma_f32_16x16x32_bf16(
                    af[i], bfr[j], acc[i][j], 0, 0, 0);
    }

    float invb[4];
    if (RDIVB) {
        #pragma unroll
        for (int j = 0; j < 4; ++j) invb[j] = 1.f / racc[j][0];
    }

    // epilogue: C/D layout col = lane&15, row = qd*4 + reg  [m89]
    #pragma unroll
    for (int i = 0; i < 4; ++i) {
        #pragma unroll
        for (int r = 0; r < 4; ++r) {
            const int m = m0 + wm + i * 16 + qd * 4 + r;
            const float rb = rowBias ? rbv[i][r] : 0.f;
            const float inv = RDIV ? (1.f / racc[i][r]) : 1.f;
            #pragma unroll
            for (int j = 0; j < 4; ++j) {
                const int n = n0 + wn + j * 16 + ln;
                float v = alpha * acc[i][j][r] + rb;
                if (colBias) v += cbv[j] + cba;
                if (EXPS) v = __expf(fminf(v, 60.f));
                if (RDIV) v *= inv;
                if (RDIVB) v *= invb[j];
                const long idx = (long)zA * sC + (long)m * ldc + n;
                if (FINAL) {
                    if (resid) v += rs[i][r][j];
                    stv(C, idx, f, v);
                } else {
                    ((bf16*)C)[idx] = __float2bfloat16(v);
                }
            }
        }
    }
}

// standalone GEMM kernel: 3D grid + XCD-bijective swizzle (m204)
template<bool FINAL, bool EXPS, bool RDIV, bool RDIVB>
__global__ __launch_bounds__(256)
void mfma_gemm(const bf16* __restrict__ A, const bf16* __restrict__ B,
               void* __restrict__ C, int K,
               int lda, int ldb, int ldc,
               long sA, long sB, long sC, int z0,
               const float* __restrict__ rowBias, long rbZ,
               const float* __restrict__ colBias, long cbZ,
               const float* __restrict__ cbase,
               float alpha, const void* __restrict__ resid, long sR,
               const int* __restrict__ flag)
{
    const int gx = gridDim.x, gy = gridDim.y;
    const int nwg = gx * gy * (int)gridDim.z;
    const int lin = blockIdx.x + gx * (blockIdx.y + gy * blockIdx.z);
    const int qq = nwg >> 3, rr = nwg & 7;
    const int xc = lin & 7, sq = lin >> 3;
    const int nl = (xc < rr ? xc * (qq + 1) : rr * (qq + 1) + (xc - rr) * qq) + sq;
    const int bxi = nl % gx;
    const int tt  = nl / gx;
    const int byi = tt % gy;
    const int bzi = tt / gy;
    gemm_dev<FINAL, EXPS, RDIV, RDIVB>(A, B, C, K, lda, ldb, ldc, sA, sB, sC, z0,
                                       rowBias, rbZ, colBias, cbZ, cbase, alpha,
                                       resid, sR, flag, bxi, byi, bzi);
}

// ---------------------------------------------------------------------------
// Dual GEMM (R10-proven): two independent plain GEMMs in ONE launch.
// Blocks [0,a.nblk) run A; rest run B.
// ---------------------------------------------------------------------------
struct GemmP {
    const bf16* A; const bf16* B; void* C;
    int K, lda, ldb, ldc;
    long sA, sB, sC;
    const float* rowBias; long rbZ;
    int gx, gy, nblk;
};

__global__ __launch_bounds__(256)
void dual_gemm_kernel(GemmP a, GemmP b)
{
    const int lin = blockIdx.x;
    const GemmP& p = (lin < a.nblk) ? a : b;
    const int sub  = (lin < a.nblk) ? lin : lin - a.nblk;
    const int nwg = p.nblk;
    const int qq = nwg >> 3, rr = nwg & 7;
    const int xc = sub & 7, sq = sub >> 3;
    const int nl = (xc < rr ? xc * (qq + 1) : rr * (qq + 1) + (xc - rr) * qq) + sq;
    const int bxi = nl % p.gx;
    const int tt  = nl / p.gx;
    const int byi = tt % p.gy;
    const int bzi = tt / p.gy;
    gemm_dev<false, false, false, false>(p.A, p.B, p.C, p.K, p.lda, p.ldb, p.ldc,
                                         p.sA, p.sB, p.sC, 0,
                                         p.rowBias, p.rbZ, nullptr, 0L, nullptr,
                                         1.f, nullptr, 0L, nullptr, bxi, byi, bzi);
}

// ---------------------------------------------------------------------------
extern "C" void kernel_launch(void* const* d_in, const int* in_sizes, int n_in,
                              void* d_out, int out_size, void* d_ws, size_t ws_size,
                              hipStream_t stream)
{
    const long NX = (long)NBATCH * CCH * HWN;
    int ix, iWq, ibq, iWk, ibk, iWv, ibv, iWo, ibo, iga, ibe;
    if (in_sizes[0] == NX) {
        ix = 0; iWq = 1; ibq = 2; iWk = 3; ibk = 4; iWv = 5; ibv = 6;
        iWo = 7; ibo = 8; iga = 9; ibe = 10;
    } else {
        iWk = 0; iWo = 1; iWq = 2; iWv = 3; ibe = 4; ibk = 5; ibo = 6;
        ibq = 7; ibv = 8; iga = 9; ix = 10;
    }
    const void* x     = d_in[ix];
    const void* Wq    = d_in[iWq];
    const void* bq    = d_in[ibq];
    const void* Wk    = d_in[iWk];
    const void* bk    = d_in[ibk];
    const void* Wv    = d_in[iWv];
    const void* bv    = d_in[ibv];
    const void* Wo    = d_in[iWo];
    const void* bo    = d_in[ibo];
    const void* gamma = d_in[iga];
    const void* beta  = d_in[ibe];

    const long CHW = (long)CCH * HWN;      // 524288
    const long NN  = (long)HWN * HWN;      // 1048576
    const size_t MB = 1ull << 20;
    const size_t KB = 1024;
    char* ws = (char*)d_ws;

    dim3 blk(256);
    const float scale = 0.044194173824159216f;   // 512^-0.5
    const float* FNUL = nullptr;
    const void*  VNUL = nullptr;

    if (ws_size >= 84 * MB) {
        // ---- associativity pipeline, dependency-compacted (R11) ----
        bf16* WkT = (bf16*)ws;                       // A z0
        bf16* Wob = (bf16*)(ws + 512 * KB);          // A z1
        bf16* WqT = (bf16*)(ws + MB);                // B z0
        bf16* WvT = (bf16*)(ws + MB + 512 * KB);     // B z1
        bf16* Mt  = (bf16*)(ws + 2 * MB);            // C z0 : Wk^T Wq
        bf16* W2  = (bf16*)(ws + 2 * MB + 512 * KB); // C z1 : Wo Wv
        float*  w1   = (float*)(ws + 3 * MB + 8 * KB);
        float*  w2   = (float*)(ws + 3 * MB + 10 * KB);
        float*  b2   = (float*)(ws + 3 * MB + 12 * KB);
        float*  c0   = (float*)(ws + 3 * MB + 14 * KB);
        float2* stats= (float2*)(ws + 3 * MB + 16 * KB);   // 4 KB
        int*    flag = (int*)(ws + 3 * MB + 20 * KB);
        float*  rowB = (float*)(ws + 3 * MB + 24 * KB);    // 64 KB
        float*  colB = (float*)(ws + 3 * MB + 88 * KB);    // 64 KB
        bf16* Zt = (bf16*)(ws + 4 * MB);             // 16 MB [b][c][j]
        bf16* S  = (bf16*)(ws + 20 * MB);            // 32 MB [b][i][j]
        bf16* yx = (bf16*)(ws + 52 * MB);            // 32 MB [b][i][1024]: y|xn

        detect_kernel<<<dim3(1), blk, 0, stream>>>(x, flag);
        // MEGA1: gn_stats(512) || prep_t(256) || zero-uv(2)
        mega1_kernel<<<dim3(770), blk, 0, stream>>>(
            x, flag, stats, Wq, Wk, Wv, Wo, WkT, WqT, WvT, Wob, rowB, colB);
        // micro (vectorized, 7 blocks) — needs prep_t outputs
        micro_kernel<<<dim3(7), blk, 0, stream>>>(WkT, WqT, Wob, bq, bk, bv, bo,
                                                  flag, w1, w2, b2, c0);
        // z=0: Mt = Wk^T Wq ; z=1: W2 = Wo Wv
        mfma_gemm<false, false, false, false><<<dim3(4, 4, 2), blk, 0, stream>>>(
            WkT, WqT, Mt, 512, 512, 512, 512, 262144L, 262144L, 262144L, 0,
            FNUL, 0L, FNUL, 0L, FNUL, 1.f, VNUL, 0L, nullptr);
        // gn(x)+SiLU -> yx[:,512:1024]; fused uv partials -> rowB/colB
        gn_apply_kernel<<<dim3(16, 8, NBATCH), blk, 0, stream>>>(
            x, flag, stats, gamma, beta, yx, w1, w2, rowB, colB, scale);
        // DUAL: y = xn@Mt^T -> yx[:,0:512]  ||  Zt = W2@xn^T + b2
        {
            GemmP py, pz;
            py.A = yx + 512; py.B = Mt; py.C = yx;
            py.K = 512; py.lda = 1024; py.ldb = 512; py.ldc = 1024;
            py.sA = 0L; py.sB = 0L; py.sC = 0L;
            py.rowBias = nullptr; py.rbZ = 0L;
            py.gx = 4; py.gy = 128; py.nblk = 512;
            pz.A = W2; pz.B = yx + 512; pz.C = Zt;
            pz.K = 512; pz.lda = 512; pz.ldb = 1024; pz.ldc = 1024;
            pz.sA = 0L; pz.sB = NN; pz.sC = CHW;
            pz.rowBias = b2; pz.rbZ = 0L;
            pz.gx = 8; pz.gy = 4; pz.nblk = 512;
            dual_gemm_kernel<<<dim3(1024), blk, 0, stream>>>(py, pz);
        }
        // S = exp(scale*(y.xn^T) + rowB_i + colB_j + scale*c0)
        mfma_gemm<false, true, false, false><<<dim3(8, 8, NBATCH), blk, 0, stream>>>(
            yx, yx + 512, S, 512, 1024, 1024, 1024, NN, NN, NN, 0,
            rowB, 1024L, colB, 1024L, c0, scale, VNUL, 0L, nullptr);
        // out[c][i] = (Zt . S^T) / rowsum(S_i) + x
        mfma_gemm<true, false, false, true><<<dim3(8, 4, NBATCH), blk, 0, stream>>>(
            Zt, S, d_out, 1024, 1024, 1024, 1024, CHW, NN, CHW, 0,
            FNUL, 0L, FNUL, 0L, FNUL, 1.f, x, CHW, flag);
    } else {
        // ---- legacy per-batch fallback (ws >= 9 MB) ----
        bf16*   Wqk   = (bf16*)ws;                         // 1 MB
        bf16*   Wvb   = (bf16*)(ws + MB);                  // 0.5 MB
        bf16*   Wob   = (bf16*)(ws + MB + MB / 2);         // 0.5 MB
        float*  bQK   = (float*)(ws + 2 * MB);
        float*  bV    = (float*)(ws + 2 * MB + 4096);
        float*  bO    = (float*)(ws + 2 * MB + 6144);
        float2* stats = (float2*)(ws + 2 * MB + 8192);
        int*    flag  = (int*)(ws + 2 * MB + 12288);
        bf16* xn = (bf16*)(ws + 3 * MB);      // 1 MB
        bf16* V  = (bf16*)(ws + 4 * MB);      // 1 MB
        bf16* QK = (bf16*)(ws + 5 * MB);      // 2 MB
        bf16* S  = (bf16*)(ws + 7 * MB);      // 2 MB
        bf16* O  = xn;

        detect_kernel<<<dim3(1), blk, 0, stream>>>(x, flag);
        // gn_stats only (mega1 roles >= 512 not launched)
        mega1_kernel<<<dim3(512), blk, 0, stream>>>(
            x, flag, stats, Wq, Wk, Wv, Wo,
            nullptr, nullptr, nullptr, nullptr, nullptr, nullptr);
        prep_kernel<<<dim3(4104), blk, 0, stream>>>(Wq, Wk, Wv, Wo, bq, bk, bv, bo,
                                                    flag, Wqk, Wvb, Wob, bQK, bV, bO);
        for (int b = 0; b < NBATCH; ++b) {
            gn_apply_old<<<dim3(16, 8, 1), blk, 0, stream>>>(
                x, flag, stats, gamma, beta, xn, b);
            mfma_gemm<false, false, false, false><<<dim3(8, 8, 1), blk, 0, stream>>>(
                xn, Wqk, QK, 512, 512, 512, 1024, 0L, 0L, 0L, 0,
                FNUL, 0L, bQK, 0L, FNUL, 1.f, VNUL, 0L, nullptr);
            mfma_gemm<false, false, false, false><<<dim3(8, 4, 1), blk, 0, stream>>>(
                Wvb, xn, V, 512, 512, 512, 1024, 0L, 0L, 0L, 0,
                bV, 0L, FNUL, 0L, FNUL, 1.f, VNUL, 0L, nullptr);
            mfma_gemm<false, true, false, false><<<dim3(8, 8, 1), blk, 0, stream>>>(
                QK, QK + 512, S, 512, 1024, 1024, 1024, 0L, 0L, 0L, b,
                FNUL, 0L, FNUL, 0L, FNUL, scale, VNUL, 0L, nullptr);
            mfma_gemm<false, false, true, false><<<dim3(4, 8, 1), blk, 0, stream>>>(
                S, V, O, 1024, 1024, 1024, 512, 0L, 0L, 0L, b,
                FNUL, 0L, FNUL, 0L, FNUL, 1.f, VNUL, 0L, nullptr);
            mfma_gemm<true, false, false, false><<<dim3(8, 4, 1), blk, 0, stream>>>(
                Wob, O, d_out, 512, 512, 512, 1024, 0L, 0L, CHW, b,
                bO, 0L, FNUL, 0L, FNUL, 1.f, x, CHW, flag);
        }
    }
}

// Round 13
// 222.457 us; speedup vs baseline: 1.2498x; 1.0688x over previous
//
#include <hip/hip_runtime.h>
#include <hip/hip_bf16.h>

#define HWN    1024
#define CCH    512
#define NBATCH 16
#define NGROUP 32
#define EPSV   1e-5f

using bf16 = __hip_bfloat16;
typedef __attribute__((ext_vector_type(4))) float f32x4;
typedef __attribute__((ext_vector_type(8))) short s16x8;

__device__ __forceinline__ float ldv(const void* p, long i, int c) {
    return c ? ((const float*)p)[i] : __bfloat162float(((const bf16*)p)[i]);
}
__device__ __forceinline__ void stv(void* p, long i, int c, float v) {
    if (c) ((float*)p)[i] = v;
    else   ((bf16*)p)[i]  = __float2bfloat16(v);
}
__device__ __forceinline__ float b2f(short s) {
    return __uint_as_float(((unsigned)(unsigned short)s) << 16);
}

// async global->LDS, 16B per lane; lds dest = wave-uniform base + lane*16
__device__ __forceinline__ void glds16(const void* g, void* l) {
    __builtin_amdgcn_global_load_lds(
        (const __attribute__((address_space(1))) void*)g,
        (__attribute__((address_space(3))) void*)l, 16, 0, 0);
}

// ---------------------------------------------------------------------------
// Inline storage-dtype detection (R12): each block scans x's first 4096
// logical bf16 slots (8 KB, L2-hot after first touch) and reduces in LDS.
// Replaces the standalone 1-block detect kernel + its dispatch gap.
// Returns f to ALL threads; leaves pool reusable (trailing barrier).
// ---------------------------------------------------------------------------
__device__ __forceinline__ int detect_dev(const void* __restrict__ x, float* pool)
{
    const int tid = threadIdx.x;
    const unsigned short* h = (const unsigned short*)x;
    int ok = 0;
    #pragma unroll
    for (int r = 0; r < 16; ++r) {
        const int i = r * 256 + tid;
        const int e = (h[2 * i] >> 7) & 0xFF;
        if (e >= 100 && e <= 135) ok++;
    }
    int* red = (int*)pool;
    red[tid] = ok; __syncthreads();
    for (int off = 128; off > 0; off >>= 1) {
        if (tid < off) red[tid] += red[tid + off];
        __syncthreads();
    }
    const int f = (red[0] < 2458) ? 1 : 0;
    __syncthreads();                       // pool reusable after this
    return f;
}

// ---------------------------------------------------------------------------
// MEGA1 (R11/R12): flag-independent front of the pipeline, one launch:
//   [0,512)   gn_stats  (inline detect; block 0 publishes flag)
//   [512,768) prep_t    (transposes + vectorized Wo copy)
//   768,769   zero rowB/colB
// ---------------------------------------------------------------------------
__device__ __forceinline__
void gn_stats_dev(const void* __restrict__ x, int f, float2* __restrict__ stats,
                  int bidx, float* pool)
{
    const int b = bidx >> 5, g = bidx & 31;
    const long base = ((long)b * CCH + (long)g * (CCH / NGROUP)) * HWN;
    const int tid = threadIdx.x;
    const int n = (CCH / NGROUP) * HWN;       // 16384
    float s = 0.f, ss = 0.f;
    if (f) {
        const float4* xp = (const float4*)((const float*)x + base);
        #pragma unroll
        for (int k = 0; k < 16; ++k) {
            float4 u = xp[tid + k * 256];
            s  += u.x + u.y + u.z + u.w;
            ss += u.x * u.x + u.y * u.y + u.z * u.z + u.w * u.w;
        }
    } else {
        for (int i = tid; i < n; i += 256) {
            float v = ldv(x, base + i, 0);
            s += v; ss += v * v;
        }
    }
    float* r1 = pool;
    float* r2 = pool + 256;
    r1[tid] = s; r2[tid] = ss; __syncthreads();
    for (int off = 128; off > 0; off >>= 1) {
        if (tid < off) { r1[tid] += r1[tid + off]; r2[tid] += r2[tid + off]; }
        __syncthreads();
    }
    if (tid == 0) {
        float mean = r1[0] / n;
        float var  = r2[0] / n - mean * mean;
        stats[bidx] = make_float2(mean, rsqrtf(var + EPSV));
    }
}

__device__ __forceinline__
void prep_t_dev(const void* __restrict__ Wq, const void* __restrict__ Wk,
                const void* __restrict__ Wv, const void* __restrict__ Wo,
                int f, bf16* __restrict__ WkT, bf16* __restrict__ WqT,
                bf16* __restrict__ WvT, bf16* __restrict__ Wob,
                int idx, float* pool)
{
    const int tid = threadIdx.x;
    if (idx < 192) {
        const int mat = idx >> 6;           // 0:Wq->WqT 1:Wk->WkT 2:Wv->WvT
        const void* src = mat == 0 ? Wq : mat == 1 ? Wk : Wv;
        bf16* dst = mat == 0 ? WqT : mat == 1 ? WkT : WvT;
        const int tile = idx & 63;
        const int r0 = (tile >> 3) * 64, c0 = (tile & 7) * 64;
        const int il = tid & 63, hq = tid >> 6;
        #pragma unroll
        for (int rr = 0; rr < 16; ++rr) {
            const int r = rr * 4 + hq;
            pool[r * 65 + il] = ldv(src, (long)(r0 + r) * 512 + c0 + il, f);
        }
        __syncthreads();
        #pragma unroll
        for (int rr = 0; rr < 16; ++rr) {
            const int cc = rr * 4 + hq;
            dst[(long)(c0 + cc) * 512 + r0 + il] = __float2bfloat16(pool[il * 65 + cc]);
        }
    } else {
        // Wo copy: 64 blocks x 4096 elems; 8-elem vector chunks per thread.
        const int base = (idx - 192) * 4096;
        #pragma unroll
        for (int pass = 0; pass < 2; ++pass) {
            const int i = base + pass * 2048 + tid * 8;
            s16x8 out;
            if (f) {
                const float4* sp = (const float4*)Wo;
                const float4 a = sp[i >> 2];
                const float4 b = sp[(i >> 2) + 1];
                out[0] = (short)(ushort)__bfloat16_as_ushort(__float2bfloat16(a.x));
                out[1] = (short)(ushort)__bfloat16_as_ushort(__float2bfloat16(a.y));
                out[2] = (short)(ushort)__bfloat16_as_ushort(__float2bfloat16(a.z));
                out[3] = (short)(ushort)__bfloat16_as_ushort(__float2bfloat16(a.w));
                out[4] = (short)(ushort)__bfloat16_as_ushort(__float2bfloat16(b.x));
                out[5] = (short)(ushort)__bfloat16_as_ushort(__float2bfloat16(b.y));
                out[6] = (short)(ushort)__bfloat16_as_ushort(__float2bfloat16(b.z));
                out[7] = (short)(ushort)__bfloat16_as_ushort(__float2bfloat16(b.w));
            } else {
                out = *(const s16x8*)((const bf16*)Wo + i);
            }
            *(s16x8*)&Wob[i] = out;
        }
    }
}

__global__ __launch_bounds__(256)
void mega1_kernel(const void* __restrict__ x, int* __restrict__ flag,
                  float2* __restrict__ stats,
                  const void* __restrict__ Wq, const void* __restrict__ Wk,
                  const void* __restrict__ Wv, const void* __restrict__ Wo,
                  bf16* __restrict__ WkT, bf16* __restrict__ WqT,
                  bf16* __restrict__ WvT, bf16* __restrict__ Wob,
                  float* __restrict__ rowB, float* __restrict__ colB)
{
    __shared__ float pool[64 * 65];      // 16.6 KB, unioned across roles
    const int bx = blockIdx.x;
    if (bx >= 768) {                     // zero rowB/colB (no detect needed)
        float4* d4 = (float4*)((bx == 768) ? rowB : colB);
        for (int i = threadIdx.x; i < 4096; i += 256)
            d4[i] = make_float4(0.f, 0.f, 0.f, 0.f);
        return;
    }
    const int f = detect_dev(x, pool);   // per-block inline detection
    if (bx == 0 && threadIdx.x == 0) flag[0] = f;   // publish for downstream
    if (bx < 512)
        gn_stats_dev(x, f, stats, bx, pool);
    else
        prep_t_dev(Wq, Wk, Wv, Wo, f, WkT, WqT, WvT, Wob, bx - 512, pool);
}

// ---------------------------------------------------------------------------
// micro device body (R9-proven vectorized form): w1 = Wk^T bq, w2 = Wq^T bk,
// b2 = Wo bv + bo, c0 = bq.bk — rows of WkT/WqT/Wob are the dot vectors.
// ---------------------------------------------------------------------------
__device__ __forceinline__
void micro_dev(const bf16* __restrict__ WkT, const bf16* __restrict__ WqT,
               const bf16* __restrict__ Wob,
               const void* __restrict__ bq, const void* __restrict__ bk,
               const void* __restrict__ bv, const void* __restrict__ bo,
               int f, float* __restrict__ w1, float* __restrict__ w2,
               float* __restrict__ b2, float* __restrict__ c0,
               int idx, float* pool)
{
    const int tid = threadIdx.x;
    if (idx < 6) {
        const void* bsrc = idx < 2 ? bq : idx < 4 ? bk : bv;
        const bf16* msrc = idx < 2 ? WkT : idx < 4 ? WqT : Wob;
        for (int i = tid; i < 512; i += 256) pool[i] = ldv(bsrc, i, f);
        __syncthreads();
        const int o = (idx & 1) * 256 + tid;
        const bf16* row = msrc + (long)o * 512;
        float s = 0.f;
        for (int k = 0; k < 512; k += 8) {
            s16x8 v = *(const s16x8*)&row[k];
            #pragma unroll
            for (int e = 0; e < 8; ++e) s += b2f(v[e]) * pool[k + e];
        }
        if (idx < 2)      w1[o] = s;
        else if (idx < 4) w2[o] = s;
        else              b2[o] = s + ldv(bo, o, f);
    } else {
        pool[tid] = ldv(bq, tid, f) * ldv(bk, tid, f)
                  + ldv(bq, tid + 256, f) * ldv(bk, tid + 256, f);
        __syncthreads();
        for (int off = 128; off > 0; off >>= 1) {
            if (tid < off) pool[tid] += pool[tid + off];
            __syncthreads();
        }
        if (tid == 0) c0[0] = pool[0];
    }
}

// ---------------------------------------------------------------------------
// Legacy prep (fallback path): Wqk=[Wq;Wk], Wvb, Wob bf16; biases f32.
// ---------------------------------------------------------------------------
__global__ __launch_bounds__(256)
void prep_kernel(const void* __restrict__ Wq, const void* __restrict__ Wk,
                 const void* __restrict__ Wv, const void* __restrict__ Wo,
                 const void* __restrict__ bq, const void* __restrict__ bk,
                 const void* __restrict__ bv, const void* __restrict__ bo,
                 const int* __restrict__ flag,
                 bf16* __restrict__ Wqk, bf16* __restrict__ Wvb, bf16* __restrict__ Wob,
                 float* __restrict__ bQK, float* __restrict__ bV, float* __restrict__ bO)
{
    const int f = flag[0];
    const int idx = blockIdx.x * 256 + threadIdx.x;
    if (idx < 524288) {
        const int r = idx >> 9, c = idx & 511;
        float v = (r < 512) ? ldv(Wq, (long)r * 512 + c, f)
                            : ldv(Wk, (long)(r - 512) * 512 + c, f);
        Wqk[idx] = __float2bfloat16(v);
    } else if (idx < 786432) {
        Wvb[idx - 524288] = __float2bfloat16(ldv(Wv, idx - 524288, f));
    } else if (idx < 1048576) {
        Wob[idx - 786432] = __float2bfloat16(ldv(Wo, idx - 786432, f));
    } else {
        const int j = idx - 1048576;
        if      (j < 512)  bQK[j]        = ldv(bq, j, f);
        else if (j < 1024) bQK[j]        = ldv(bk, j - 512, f);
        else if (j < 1536) bV[j - 1024]  = ldv(bv, j - 1024, f);
        else if (j < 2048) bO[j - 1536]  = ldv(bo, j - 1536, f);
    }
}

// ---------------------------------------------------------------------------
// GN+SiLU with transpose INTO yx right half + fused uv partials (R9 proven).
// ---------------------------------------------------------------------------
__global__ __launch_bounds__(256)
void gn_apply_kernel(const void* __restrict__ x, const int* __restrict__ flag,
                     const float2* __restrict__ stats,
                     const void* __restrict__ gamma, const void* __restrict__ beta,
                     bf16* __restrict__ yx,
                     const float* __restrict__ w1, const float* __restrict__ w2,
                     float* __restrict__ rowB, float* __restrict__ colB,
                     float scale)
{
    const int f = flag[0];
    __shared__ float t[64][65];
    __shared__ float redu[4][64], redv[4][64];
    const int gx = gridDim.x, gy = gridDim.y;
    const int nwg = gx * gy * (int)gridDim.z;
    const int lin = blockIdx.x + gx * (blockIdx.y + gy * blockIdx.z);
    const int qq = nwg >> 3, rr = nwg & 7;
    const int xc = lin & 7, sq = lin >> 3;
    const int nl = (xc < rr ? xc * (qq + 1) : rr * (qq + 1) + (xc - rr) * qq) + sq;
    const int bxi = nl % gx;
    const int tt  = nl / gx;
    const int byi = tt % gy;
    const int bz  = tt / gy;

    const int i0 = bxi * 64;
    const int c0 = byi * 64;
    const int tid = threadIdx.x;
    const int il = tid & 63;
    const int hq = tid >> 6;              // 0..3
    float su = 0.f, sv = 0.f;
    #pragma unroll
    for (int r = 0; r < 16; ++r) {
        const int cl = r * 4 + hq;
        const int c = c0 + cl;
        const float2 st = stats[bz * NGROUP + (c >> 4)];
        const float ga = ldv(gamma, c, f), be = ldv(beta, c, f);
        float v = ldv(x, (long)bz * CCH * HWN + (long)c * HWN + i0 + il, f);
        v = (v - st.x) * st.y * ga + be;
        const float s = v / (1.f + __expf(-v));     // SiLU
        t[cl][il] = s;
        su += s * w1[c];
        sv += s * w2[c];
    }
    redu[hq][il] = su;
    redv[hq][il] = sv;
    __syncthreads();
    #pragma unroll
    for (int r = 0; r < 16; ++r) {
        const int ii = r * 4 + hq;
        yx[(long)bz * (HWN * (long)HWN) + (long)(i0 + ii) * 1024 + 512 + c0 + il] =
            __float2bfloat16(t[il][ii]);
    }
    if (tid < 64) {
        const float s1 = redu[0][tid] + redu[1][tid] + redu[2][tid] + redu[3][tid];
        const float s2 = redv[0][tid] + redv[1][tid] + redv[2][tid] + redv[3][tid];
        const long gi = (long)bz * HWN + i0 + tid;
        atomicAdd(&colB[gi], scale * s1);   // u-side -> colB
        atomicAdd(&rowB[gi], scale * s2);   // v-side -> rowB
    }
}

// legacy (fallback) gn: x -> xn [i][c], stride 512, per-batch
__global__ __launch_bounds__(256)
void gn_apply_old(const void* __restrict__ x, const int* __restrict__ flag,
                  const float2* __restrict__ stats,
                  const void* __restrict__ gamma, const void* __restrict__ beta,
                  bf16* __restrict__ xn, int zb)
{
    const int f = flag[0];
    __shared__ float t[64][65];
    const int bx = zb + blockIdx.z;
    const int i0 = blockIdx.x * 64;
    const int c0 = blockIdx.y * 64;
    const int tid = threadIdx.x;
    const int il = tid & 63;
    const int hq = tid >> 6;
    #pragma unroll
    for (int r = 0; r < 16; ++r) {
        const int cl = r * 4 + hq;
        const int c = c0 + cl;
        const float2 st = stats[bx * NGROUP + (c >> 4)];
        const float ga = ldv(gamma, c, f), be = ldv(beta, c, f);
        float v = ldv(x, (long)bx * CCH * HWN + (long)c * HWN + i0 + il, f);
        v = (v - st.x) * st.y * ga + be;
        t[cl][il] = v / (1.f + __expf(-v));
    }
    __syncthreads();
    #pragma unroll
    for (int r = 0; r < 16; ++r) {
        const int ii = r * 4 + hq;
        xn[(long)blockIdx.z * CCH * HWN + (long)(i0 + ii) * CCH + c0 + il] =
            __float2bfloat16(t[il][ii]);
    }
}

// ---------------------------------------------------------------------------
// MFMA TN GEMM device core (proven): C[m][n] = alpha*sum_k A[m][k]B[n][k].
// 128x128 tile, BK=32, 4 waves, glds16 dbuf + XOR swizzle.
// EXPS/RDIV/RDIVB/FINAL hooks + R7/R9 register prefetch of epilogue inputs.
// ---------------------------------------------------------------------------
template<bool FINAL, bool EXPS, bool RDIV, bool RDIVB>
__device__ __forceinline__
void gemm_dev(const bf16* __restrict__ A, const bf16* __restrict__ B,
              void* __restrict__ C, int K,
              int lda, int ldb, int ldc,
              long sA, long sB, long sC, int z0,
              const float* __restrict__ rowBias, long rbZ,
              const float* __restrict__ colBias, long cbZ,
              const float* __restrict__ cbase,
              float alpha, const void* __restrict__ resid, long sR,
              const int* __restrict__ flag,
              int bxi, int byi, int bzi)
{
    __shared__ bf16 lA[2][128 * 32];
    __shared__ bf16 lB[2][128 * 32];

    const int tid = threadIdx.x;
    const int w   = tid >> 6;
    const int l   = tid & 63;
    const int ln  = l & 15;
    const int qd  = l >> 4;
    const int wm  = (w >> 1) * 64;
    const int wn  = (w & 1) * 64;
    const int zA  = z0 + bzi;

    const bf16* Ab = A + (long)zA * sA;
    const bf16* Bb = B + (long)zA * sB;
    const int m0 = byi * 128;
    const int n0 = bxi * 128;

    const int sr   = l >> 2;
    const int kswz = ((l & 3) ^ ((l >> 3) & 3)) * 8;
    const bf16* gA0 = Ab + (long)(m0 + w * 16 + sr) * lda + kswz;
    const bf16* gA1 = gA0 + (long)64 * lda;
    const bf16* gB0 = Bb + (long)(n0 + w * 16 + sr) * ldb + kswz;
    const bf16* gB1 = gB0 + (long)64 * ldb;

    f32x4 acc[4][4];
    #pragma unroll
    for (int i = 0; i < 4; ++i)
        #pragma unroll
        for (int j = 0; j < 4; ++j)
            acc[i][j] = (f32x4){0.f, 0.f, 0.f, 0.f};

    f32x4 racc[4];
    #pragma unroll
    for (int i = 0; i < 4; ++i) racc[i] = (f32x4){0.f, 0.f, 0.f, 0.f};
    s16x8 ones;
    #pragma unroll
    for (int e = 0; e < 8; ++e) ones[e] = (short)0x3F80;   // bf16 1.0

    const int swA = (qd ^ ((ln >> 1) & 3)) * 8;

    glds16(gA0, &lA[0][w * 512]);
    glds16(gA1, &lA[0][2048 + w * 512]);
    glds16(gB0, &lB[0][w * 512]);
    glds16(gB1, &lB[0][2048 + w * 512]);

    // Prefetch all epilogue inputs into registers NOW (hide under K-loop).
    const int f = (FINAL && flag) ? flag[0] : 0;
    float rs[4][4][4];
    float rbv[4][4], cbv[4];
    float cba = 0.f;
    {
        if (rowBias) {
            #pragma unroll
            for (int i = 0; i < 4; ++i)
                #pragma unroll
                for (int r = 0; r < 4; ++r)
                    rbv[i][r] = rowBias[(long)zA * rbZ + m0 + wm + i * 16 + qd * 4 + r];
        }
        if (colBias) {
            #pragma unroll
            for (int j = 0; j < 4; ++j)
                cbv[j] = colBias[(long)zA * cbZ + n0 + wn + j * 16 + ln];
            if (cbase) cba = alpha * cbase[0];
        }
        if (FINAL && resid) {
            #pragma unroll
            for (int i = 0; i < 4; ++i)
                #pragma unroll
                for (int r = 0; r < 4; ++r) {
                    const int m = m0 + wm + i * 16 + qd * 4 + r;
                    #pragma unroll
                    for (int j = 0; j < 4; ++j) {
                        const int n = n0 + wn + j * 16 + ln;
                        rs[i][r][j] = ldv(resid, (long)zA * sR + (long)m * ldc + n, f);
                    }
                }
        }
        __builtin_amdgcn_sched_barrier(0);   // pin prefetch before the K-loop
    }

    const int NK = K >> 5;
    for (int t = 0; t < NK; ++t) {
        const int p = t & 1;
        __syncthreads();
        if (t + 1 < NK) {
            const int kk = (t + 1) << 5;
            glds16(gA0 + kk, &lA[p ^ 1][w * 512]);
            glds16(gA1 + kk, &lA[p ^ 1][2048 + w * 512]);
            glds16(gB0 + kk, &lB[p ^ 1][w * 512]);
            glds16(gB1 + kk, &lB[p ^ 1][2048 + w * 512]);
        }
        s16x8 af[4], bfr[4];
        #pragma unroll
        for (int i = 0; i < 4; ++i)
            af[i] = *(const s16x8*)&lA[p][(wm + i * 16 + ln) * 32 + swA];
        #pragma unroll
        for (int j = 0; j < 4; ++j)
            bfr[j] = *(const s16x8*)&lB[p][(wn + j * 16 + ln) * 32 + swA];
        if (RDIV) {
            #pragma unroll
            for (int i = 0; i < 4; ++i)
                racc[i] = __builtin_amdgcn_mfma_f32_16x16x32_bf16(
                    af[i], ones, racc[i], 0, 0, 0);
        }
        if (RDIVB) {
            #pragma unroll
            for (int j = 0; j < 4; ++j)
                racc[j] = __builtin_amdgcn_mfma_f32_16x16x32_bf16(
                    ones, bfr[j], racc[j], 0, 0, 0);
        }
        #pragma unroll
        for (int i = 0; i < 4; ++i)
            #pragma unroll
            for (int j = 0; j < 4; ++j)
                acc[i][j] = __builtin_amdgcn_mfma_f32_16x16x32_bf16(
                    af[i], bfr[j], acc[i][j], 0, 0, 0);
    }

    float invb[4];
    if (RDIVB) {
        #pragma unroll
        for (int j = 0; j < 4; ++j) invb[j] = 1.f / racc[j][0];
    }

    // epilogue: C/D layout col = lane&15, row = qd*4 + reg  [m89]
    #pragma unroll
    for (int i = 0; i < 4; ++i) {
        #pragma unroll
        for (int r = 0; r < 4; ++r) {
            const int m = m0 + wm + i * 16 + qd * 4 + r;
            const float rb = rowBias ? rbv[i][r] : 0.f;
            const float inv = RDIV ? (1.f / racc[i][r]) : 1.f;
            #pragma unroll
            for (int j = 0; j < 4; ++j) {
                const int n = n0 + wn + j * 16 + ln;
                float v = alpha * acc[i][j][r] + rb;
                if (colBias) v += cbv[j] + cba;
                if (EXPS) v = __expf(fminf(v, 60.f));
                if (RDIV) v *= inv;
                if (RDIVB) v *= invb[j];
                const long idx = (long)zA * sC + (long)m * ldc + n;
                if (FINAL) {
                    if (resid) v += rs[i][r][j];
                    stv(C, idx, f, v);
                } else {
                    ((bf16*)C)[idx] = __float2bfloat16(v);
                }
            }
        }
    }
}

// standalone GEMM kernel: 3D grid + XCD-bijective swizzle (m204)
template<bool FINAL, bool EXPS, bool RDIV, bool RDIVB>
__global__ __launch_bounds__(256)
void mfma_gemm(const bf16* __restrict__ A, const bf16* __restrict__ B,
               void* __restrict__ C, int K,
               int lda, int ldb, int ldc,
               long sA, long sB, long sC, int z0,
               const float* __restrict__ rowBias, long rbZ,
               const float* __restrict__ colBias, long cbZ,
               const float* __restrict__ cbase,
               float alpha, const void* __restrict__ resid, long sR,
               const int* __restrict__ flag)
{
    const int gx = gridDim.x, gy = gridDim.y;
    const int nwg = gx * gy * (int)gridDim.z;
    const int lin = blockIdx.x + gx * (blockIdx.y + gy * blockIdx.z);
    const int qq = nwg >> 3, rr = nwg & 7;
    const int xc = lin & 7, sq = lin >> 3;
    const int nl = (xc < rr ? xc * (qq + 1) : rr * (qq + 1) + (xc - rr) * qq) + sq;
    const int bxi = nl % gx;
    const int tt  = nl / gx;
    const int byi = tt % gy;
    const int bzi = tt / gy;
    gemm_dev<FINAL, EXPS, RDIV, RDIVB>(A, B, C, K, lda, ldb, ldc, sA, sB, sC, z0,
                                       rowBias, rbZ, colBias, cbZ, cbase, alpha,
                                       resid, sR, flag, bxi, byi, bzi);
}

// ---------------------------------------------------------------------------
// MEGA2 (R12): MtW2 GEMM (32 blocks) || micro (7 blocks) in one launch.
// Both depend only on mega1's prep_t outputs.
// ---------------------------------------------------------------------------
__global__ __launch_bounds__(256)
void mega2_kernel(const bf16* __restrict__ WkT, const bf16* __restrict__ WqT,
                  const bf16* __restrict__ Wob, bf16* __restrict__ Mt,
                  const void* __restrict__ bq, const void* __restrict__ bk,
                  const void* __restrict__ bv, const void* __restrict__ bo,
                  const int* __restrict__ flag,
                  float* __restrict__ w1, float* __restrict__ w2,
                  float* __restrict__ b2, float* __restrict__ c0)
{
    __shared__ float pool[512];
    const int bx = blockIdx.x;
    if (bx < 32) {
        // z=0: Mt = Wk^T Wq ; z=1: W2 = Wo Wv  (strided at 262144 elems)
        const int z = bx >> 4, t = bx & 15;
        gemm_dev<false, false, false, false>(
            WkT, WqT, Mt, 512, 512, 512, 512, 262144L, 262144L, 262144L, 0,
            nullptr, 0L, nullptr, 0L, nullptr, 1.f, nullptr, 0L, nullptr,
            t & 3, t >> 2, z);
    } else {
        micro_dev(WkT, WqT, Wob, bq, bk, bv, bo, flag[0],
                  w1, w2, b2, c0, bx - 32, pool);
    }
}

// ---------------------------------------------------------------------------
// Dual GEMM (R10-proven): two independent plain GEMMs in ONE launch.
// Blocks [0,a.nblk) run A; rest run B.
// ---------------------------------------------------------------------------
struct GemmP {
    const bf16* A; const bf16* B; void* C;
    int K, lda, ldb, ldc;
    long sA, sB, sC;
    const float* rowBias; long rbZ;
    int gx, gy, nblk;
};

__global__ __launch_bounds__(256)
void dual_gemm_kernel(GemmP a, GemmP b)
{
    const int lin = blockIdx.x;
    const GemmP& p = (lin < a.nblk) ? a : b;
    const int sub  = (lin < a.nblk) ? lin : lin - a.nblk;
    const int nwg = p.nblk;
    const int qq = nwg >> 3, rr = nwg & 7;
    const int xc = sub & 7, sq = sub >> 3;
    const int nl = (xc < rr ? xc * (qq + 1) : rr * (qq + 1) + (xc - rr) * qq) + sq;
    const int bxi = nl % p.gx;
    const int tt  = nl / p.gx;
    const int byi = tt % p.gy;
    const int bzi = tt / p.gy;
    gemm_dev<false, false, false, false>(p.A, p.B, p.C, p.K, p.lda, p.ldb, p.ldc,
                                         p.sA, p.sB, p.sC, 0,
                                         p.rowBias, p.rbZ, nullptr, 0L, nullptr,
                                         1.f, nullptr, 0L, nullptr, bxi, byi, bzi);
}

// ---------------------------------------------------------------------------
extern "C" void kernel_launch(void* const* d_in, const int* in_sizes, int n_in,
                              void* d_out, int out_size, void* d_ws, size_t ws_size,
                              hipStream_t stream)
{
    const long NX = (long)NBATCH * CCH * HWN;
    int ix, iWq, ibq, iWk, ibk, iWv, ibv, iWo, ibo, iga, ibe;
    if (in_sizes[0] == NX) {
        ix = 0; iWq = 1; ibq = 2; iWk = 3; ibk = 4; iWv = 5; ibv = 6;
        iWo = 7; ibo = 8; iga = 9; ibe = 10;
    } else {
        iWk = 0; iWo = 1; iWq = 2; iWv = 3; ibe = 4; ibk = 5; ibo = 6;
        ibq = 7; ibv = 8; iga = 9; ix = 10;
    }
    const void* x     = d_in[ix];
    const void* Wq    = d_in[iWq];
    const void* bq    = d_in[ibq];
    const void* Wk    = d_in[iWk];
    const void* bk    = d_in[ibk];
    const void* Wv    = d_in[iWv];
    const void* bv    = d_in[ibv];
    const void* Wo    = d_in[iWo];
    const void* bo    = d_in[ibo];
    const void* gamma = d_in[iga];
    const void* beta  = d_in[ibe];

    const long CHW = (long)CCH * HWN;      // 524288
    const long NN  = (long)HWN * HWN;      // 1048576
    const size_t MB = 1ull << 20;
    const size_t KB = 1024;
    char* ws = (char*)d_ws;

    dim3 blk(256);
    const float scale = 0.044194173824159216f;   // 512^-0.5
    const float* FNUL = nullptr;
    const void*  VNUL = nullptr;

    if (ws_size >= 84 * MB) {
        // ---- associativity pipeline, 6 dispatches (R12) ----
        bf16* WkT = (bf16*)ws;                       // A z0
        bf16* Wob = (bf16*)(ws + 512 * KB);          // A z1
        bf16* WqT = (bf16*)(ws + MB);                // B z0
        bf16* WvT = (bf16*)(ws + MB + 512 * KB);     // B z1
        bf16* Mt  = (bf16*)(ws + 2 * MB);            // C z0 : Wk^T Wq
        bf16* W2  = (bf16*)(ws + 2 * MB + 512 * KB); // C z1 : Wo Wv
        float*  w1   = (float*)(ws + 3 * MB + 8 * KB);
        float*  w2   = (float*)(ws + 3 * MB + 10 * KB);
        float*  b2   = (float*)(ws + 3 * MB + 12 * KB);
        float*  c0   = (float*)(ws + 3 * MB + 14 * KB);
        float2* stats= (float2*)(ws + 3 * MB + 16 * KB);   // 4 KB
        int*    flag = (int*)(ws + 3 * MB + 20 * KB);
        float*  rowB = (float*)(ws + 3 * MB + 24 * KB);    // 64 KB
        float*  colB = (float*)(ws + 3 * MB + 88 * KB);    // 64 KB
        bf16* Zt = (bf16*)(ws + 4 * MB);             // 16 MB [b][c][j]
        bf16* S  = (bf16*)(ws + 20 * MB);            // 32 MB [b][i][j]
        bf16* yx = (bf16*)(ws + 52 * MB);            // 32 MB [b][i][1024]: y|xn

        // MEGA1: inline-detect + gn_stats(512) || prep_t(256) || zero-uv(2)
        mega1_kernel<<<dim3(770), blk, 0, stream>>>(
            x, flag, stats, Wq, Wk, Wv, Wo, WkT, WqT, WvT, Wob, rowB, colB);
        // MEGA2: MtW2 GEMM(32) || micro(7)
        mega2_kernel<<<dim3(39), blk, 0, stream>>>(
            WkT, WqT, Wob, Mt, bq, bk, bv, bo, flag, w1, w2, b2, c0);
        // gn(x)+SiLU -> yx[:,512:1024]; fused uv partials -> rowB/colB
        gn_apply_kernel<<<dim3(16, 8, NBATCH), blk, 0, stream>>>(
            x, flag, stats, gamma, beta, yx, w1, w2, rowB, colB, scale);
        // DUAL: y = xn@Mt^T -> yx[:,0:512]  ||  Zt = W2@xn^T + b2
        {
            GemmP py, pz;
            py.A = yx + 512; py.B = Mt; py.C = yx;
            py.K = 512; py.lda = 1024; py.ldb = 512; py.ldc = 1024;
            py.sA = 0L; py.sB = 0L; py.sC = 0L;
            py.rowBias = nullptr; py.rbZ = 0L;
            py.gx = 4; py.gy = 128; py.nblk = 512;
            pz.A = W2; pz.B = yx + 512; pz.C = Zt;
            pz.K = 512; pz.lda = 512; pz.ldb = 1024; pz.ldc = 1024;
            pz.sA = 0L; pz.sB = NN; pz.sC = CHW;
            pz.rowBias = b2; pz.rbZ = 0L;
            pz.gx = 8; pz.gy = 4; pz.nblk = 512;
            dual_gemm_kernel<<<dim3(1024), blk, 0, stream>>>(py, pz);
        }
        // S = exp(scale*(y.xn^T) + rowB_i + colB_j + scale*c0)
        mfma_gemm<false, true, false, false><<<dim3(8, 8, NBATCH), blk, 0, stream>>>(
            yx, yx + 512, S, 512, 1024, 1024, 1024, NN, NN, NN, 0,
            rowB, 1024L, colB, 1024L, c0, scale, VNUL, 0L, nullptr);
        // out[c][i] = (Zt . S^T) / rowsum(S_i) + x
        mfma_gemm<true, false, false, true><<<dim3(8, 4, NBATCH), blk, 0, stream>>>(
            Zt, S, d_out, 1024, 1024, 1024, 1024, CHW, NN, CHW, 0,
            FNUL, 0L, FNUL, 0L, FNUL, 1.f, x, CHW, flag);
    } else {
        // ---- legacy per-batch fallback (ws >= 9 MB) ----
        bf16*   Wqk   = (bf16*)ws;                         // 1 MB
        bf16*   Wvb   = (bf16*)(ws + MB);                  // 0.5 MB
        bf16*   Wob   = (bf16*)(ws + MB + MB / 2);         // 0.5 MB
        float*  bQK   = (float*)(ws + 2 * MB);
        float*  bV    = (float*)(ws + 2 * MB + 4096);
        float*  bO    = (float*)(ws + 2 * MB + 6144);
        float2* stats = (float2*)(ws + 2 * MB + 8192);
        int*    flag  = (int*)(ws + 2 * MB + 12288);
        bf16* xn = (bf16*)(ws + 3 * MB);      // 1 MB
        bf16* V  = (bf16*)(ws + 4 * MB);      // 1 MB
        bf16* QK = (bf16*)(ws + 5 * MB);      // 2 MB
        bf16* S  = (bf16*)(ws + 7 * MB);      // 2 MB
        bf16* O  = xn;

        // gn_stats (with inline detect; block 0 publishes flag)
        mega1_kernel<<<dim3(512), blk, 0, stream>>>(
            x, flag, stats, Wq, Wk, Wv, Wo,
            nullptr, nullptr, nullptr, nullptr, nullptr, nullptr);
        prep_kernel<<<dim3(4104), blk, 0, stream>>>(Wq, Wk, Wv, Wo, bq, bk, bv, bo,
                                                    flag, Wqk, Wvb, Wob, bQK, bV, bO);
        for (int b = 0; b < NBATCH; ++b) {
            gn_apply_old<<<dim3(16, 8, 1), blk, 0, stream>>>(
                x, flag, stats, gamma, beta, xn, b);
            mfma_gemm<false, false, false, false><<<dim3(8, 8, 1), blk, 0, stream>>>(
                xn, Wqk, QK, 512, 512, 512, 1024, 0L, 0L, 0L, 0,
                FNUL, 0L, bQK, 0L, FNUL, 1.f, VNUL, 0L, nullptr);
            mfma_gemm<false, false, false, false><<<dim3(8, 4, 1), blk, 0, stream>>>(
                Wvb, xn, V, 512, 512, 512, 1024, 0L, 0L, 0L, 0,
                bV, 0L, FNUL, 0L, FNUL, 1.f, VNUL, 0L, nullptr);
            mfma_gemm<false, true, false, false><<<dim3(8, 8, 1), blk, 0, stream>>>(
                QK, QK + 512, S, 512, 1024, 1024, 1024, 0L, 0L, 0L, b,
                FNUL, 0L, FNUL, 0L, FNUL, scale, VNUL, 0L, nullptr);
            mfma_gemm<false, false, true, false><<<dim3(4, 8, 1), blk, 0, stream>>>(
                S, V, O, 1024, 1024, 1024, 512, 0L, 0L, 0L, b,
                FNUL, 0L, FNUL, 0L, FNUL, 1.f, VNUL, 0L, nullptr);
            mfma_gemm<true, false, false, false><<<dim3(8, 4, 1), blk, 0, stream>>>(
                Wob, O, d_out, 512, 512, 512, 1024, 0L, 0L, CHW, b,
                bO, 0L, FNUL, 0L, FNUL, 1.f, x, CHW, flag);
        }
    }
}